// Round 12
// baseline (539.086 us; speedup 1.0000x reference)
//
#include <hip/hip_runtime.h>
#include <hip/hip_bf16.h>
#include <cstdint>
#include <cstddef>

#define Bdim 2
#define Sdim 2048
#define Edim 1024
#define Hdim 16
#define Ddim 64
#define KVB 128
#define MROWS (Bdim*Sdim)

typedef __bf16 bf16_t;
typedef __attribute__((ext_vector_type(8))) __bf16 bf16x8;
typedef __attribute__((ext_vector_type(4))) __bf16 bf16x4;
typedef __attribute__((ext_vector_type(4))) float f32x4;

__device__ inline bf16_t f2b(float x) {
    unsigned u = __builtin_bit_cast(unsigned, x);
    unsigned r = u + 0x7fffu + ((u >> 16) & 1u);
    return __builtin_bit_cast(bf16_t, (unsigned short)(r >> 16));
}

// Stage a ROWS x 32 tile (row-major, leading dim ld) into LDS as bf16, rows
// padded to 40 elements. Converts f32 -> bf16 on the fly when T == float.
template<typename T, int ROWS>
__device__ inline void stage_tile(bf16_t* dst, const T* src, int ld, int tid) {
    for (int i = tid; i < ROWS * 4; i += 256) {
        int r = i >> 2;
        int c = (i & 3) * 8;
        const T* s = src + (size_t)r * ld + c;
        bf16x8 v;
        if constexpr (sizeof(T) == 4) {
            const float4* sf = (const float4*)s;
            float4 a = sf[0], b = sf[1];
            v[0] = f2b(a.x); v[1] = f2b(a.y); v[2] = f2b(a.z); v[3] = f2b(a.w);
            v[4] = f2b(b.x); v[5] = f2b(b.y); v[6] = f2b(b.z); v[7] = f2b(b.w);
        } else {
            v = *(const bf16x8*)s;
        }
        *(bf16x8*)(dst + r * 40 + c) = v;
    }
}

// Core: C[128 x BN] += A[128 x K] * B^T, B row-major [BN x K]. 4 waves 2x2.
template<typename TA, typename TB, int FN>
__device__ inline void gemm_core(const TA* A, int lda, const TB* B, int ldb, int K,
                                 f32x4 (&acc)[4][FN]) {
    constexpr int BN = FN * 32;
    __shared__ bf16_t As[128 * 40];
    __shared__ bf16_t Bs[BN * 40];
    const int tid = threadIdx.x;
    const int lane = tid & 63;
    const int w = tid >> 6;
    const int wm = w >> 1, wn = w & 1;
    const int lr = lane & 15, lg = lane >> 4;

    #pragma unroll
    for (int mi = 0; mi < 4; ++mi)
        #pragma unroll
        for (int ni = 0; ni < FN; ++ni)
            acc[mi][ni] = (f32x4){0.f, 0.f, 0.f, 0.f};

    for (int kt = 0; kt < K; kt += 32) {
        __syncthreads();
        stage_tile<TA, 128>(As, A + kt, lda, tid);
        stage_tile<TB, BN>(Bs, B + kt, ldb, tid);
        __syncthreads();
        bf16x8 af[4], bf[FN];
        #pragma unroll
        for (int mi = 0; mi < 4; ++mi)
            af[mi] = *(const bf16x8*)&As[(wm * 64 + mi * 16 + lr) * 40 + lg * 8];
        #pragma unroll
        for (int ni = 0; ni < FN; ++ni)
            bf[ni] = *(const bf16x8*)&Bs[(wn * (FN * 16) + ni * 16 + lr) * 40 + lg * 8];
        #pragma unroll
        for (int mi = 0; mi < 4; ++mi)
            #pragma unroll
            for (int ni = 0; ni < FN; ++ni)
                acc[mi][ni] = __builtin_amdgcn_mfma_f32_16x16x32_bf16(
                    af[mi], bf[ni], acc[mi][ni], 0, 0, 0);
    }
}

// ---- Kernel 0: convert the 4 weight matrices to bf16; Wq scaled by 0.125.
__global__ __launch_bounds__(256) void k_convert(
    const float* __restrict__ Wq, const float* __restrict__ Wk,
    const float* __restrict__ Wv, const float* __restrict__ Wo,
    bf16_t* __restrict__ dst) {
    const int z = blockIdx.y;
    const float* src = (z == 0) ? Wq : (z == 1) ? Wk : (z == 2) ? Wv : Wo;
    const float scale = (z == 0) ? 0.125f : 1.0f;
    bf16_t* d = dst + (size_t)z * Edim * Edim;
    const int i = blockIdx.x * 256 + threadIdx.x;
    const float4* s4 = (const float4*)(src + (size_t)i * 8);
    float4 a = s4[0], b = s4[1];
    bf16x8 v;
    v[0] = f2b(a.x * scale); v[1] = f2b(a.y * scale);
    v[2] = f2b(a.z * scale); v[3] = f2b(a.w * scale);
    v[4] = f2b(b.x * scale); v[5] = f2b(b.y * scale);
    v[6] = f2b(b.z * scale); v[7] = f2b(b.w * scale);
    *(bf16x8*)(d + (size_t)i * 8) = v;
}

// ---- Kernel 1: QKV projections. z = 0/1/2 -> Q/K/V. W pre-converted bf16.
// Q (pre-scaled by 0.125) -> [B,H,S,D]; K,V -> MFMA-fragment-major swizzled:
//   Kswz[bh][s/16][d/8][s%16][d%8]
//   Vswz[bh][s/32][d/16][(s/8)%4][d%16][s%8]
__global__ __launch_bounds__(256) void k_proj(
    const float* __restrict__ xq, const float* __restrict__ xk, const float* __restrict__ xv,
    const bf16_t* __restrict__ Wb,
    const float* __restrict__ bq, const float* __restrict__ bk, const float* __restrict__ bv,
    bf16_t* __restrict__ Qb, bf16_t* __restrict__ Kswz, bf16_t* __restrict__ Vswz) {
    const int z = blockIdx.z;
    const float* X = (z == 0) ? xq : (z == 1) ? xk : xv;
    const bf16_t* W = Wb + (size_t)z * Edim * Edim;
    const float* bias = (z == 0) ? bq : (z == 1) ? bk : bv;
    const float bscale = (z == 0) ? 0.125f : 1.0f;
    const int tm = blockIdx.y, tn = blockIdx.x;
    f32x4 acc[4][4];
    gemm_core<float, bf16_t, 4>(X + (size_t)tm * 128 * Edim, Edim,
                                W + (size_t)tn * 128 * Edim, Edim, Edim, acc);
    const int tid = threadIdx.x, lane = tid & 63, w = tid >> 6;
    const int wm = w >> 1, wn = w & 1, lr = lane & 15, lg = lane >> 4;
    #pragma unroll
    for (int mi = 0; mi < 4; ++mi)
        #pragma unroll
        for (int ni = 0; ni < 4; ++ni)
            #pragma unroll
            for (int j = 0; j < 4; ++j) {
                int gm = tm * 128 + wm * 64 + mi * 16 + lg * 4 + j;
                int gn = tn * 128 + wn * 64 + ni * 16 + lr;
                float v = acc[mi][ni][j] + bias[gn] * bscale;
                int b = gm >> 11, s = gm & (Sdim - 1);
                int h = gn >> 6, d = gn & (Ddim - 1);
                size_t bh = (size_t)(b * Hdim + h);
                if (z == 0) {
                    Qb[(bh * Sdim + s) * Ddim + d] = f2b(v);
                } else if (z == 1) {
                    size_t idx = ((bh * (Sdim / 16) + (s >> 4)) * 8 + (d >> 3)) * 128
                               + (s & 15) * 8 + (d & 7);
                    Kswz[idx] = f2b(v);
                } else {
                    size_t idx = (((bh * (Sdim / 32) + (s >> 5)) * 4 + (d >> 4)) * 4
                               + ((s >> 3) & 3)) * 128 + (d & 15) * 8 + (s & 7);
                    Vswz[idx] = f2b(v);
                }
            }
}

// ---- Kernel 2: fused attention v9 — COLUMN-SPLIT waves.
// 64-row blocks; wave w owns k-cols [w*512,(w+1)*512) for ALL 64 rows.
// K/V read ONCE per block (4x cut vs r9) with ZERO main-loop barriers.
// Phase 1: per-wave partial row sums -> LDS reduce (1 barrier).
// Phase 2: per wave: scores->exp->band (LDS), coalesced P store (own col
// stripe), PV partial accumulate; then one LDS reduction of O (2 barriers).
__global__ __launch_bounds__(256) void k_attn(
    const bf16_t* __restrict__ Qb, const bf16_t* __restrict__ Kswz,
    const bf16_t* __restrict__ Vswz, float* __restrict__ P, bf16_t* __restrict__ AOb) {
    const int wg = blockIdx.x;
    const int id = ((wg & 7) << 7) | (wg >> 3);   // bijective XCD swizzle
    const int bh = id >> 5, qt = id & 31;
    const int b = bh >> 4, h = bh & 15;
    const int tid = threadIdx.x, lane = tid & 63, w = tid >> 6;
    const int lr = lane & 15, lg = lane >> 4;

    // LDS: 4 per-wave P bands 64x134 bf16 (68608B), ALIASED with the 64KB
    // O-reduction buffer red[4][64][64] f32 (barrier separates uses);
    // sum_lds beyond both.
    __shared__ __align__(16) unsigned char smem[69632];
    bf16_t* Psw = (bf16_t*)smem + (size_t)w * 64 * 134;
    float* redf = (float*)smem;                       // red[w][row][d]
    float* sum_lds = (float*)(smem + 68608);          // [4][64]

    const bf16_t* Qp = Qb + ((size_t)bh * Sdim + qt * 64) * Ddim;
    const bf16_t* Kp = Kswz + (size_t)bh * Sdim * Ddim;
    const bf16_t* Vp = Vswz + (size_t)bh * Ddim * Sdim;
    float* Pp = P + (size_t)bh * Sdim * Sdim + (size_t)(qt * 64) * Sdim;

    // Q fragments for ALL 64 block rows (pre-scaled by 1/8 at projection).
    bf16x8 qf[4][2];
    #pragma unroll
    for (int rg = 0; rg < 4; ++rg)
        #pragma unroll
        for (int kk = 0; kk < 2; ++kk)
            qf[rg][kk] = *(const bf16x8*)(Qp + (rg * 16 + lr) * Ddim + kk * 32 + lg * 8);

    // ---------------- Phase 1: partial row sums over this wave's cols ------
    float lsum[4][4];
    #pragma unroll
    for (int rg = 0; rg < 4; ++rg)
        #pragma unroll
        for (int j = 0; j < 4; ++j) lsum[rg][j] = 0.f;

    for (int t = 0; t < 4; ++t) {
        const int kt = w * 4 + t;
        #pragma unroll
        for (int ni = 0; ni < 8; ++ni) {
            const bf16_t* kp = Kp + (size_t)(kt * 8 + ni) * 1024 + lane * 8;
            bf16x8 kf0 = *(const bf16x8*)(kp);
            bf16x8 kf1 = *(const bf16x8*)(kp + 512);
            #pragma unroll
            for (int rg = 0; rg < 4; ++rg) {
                f32x4 s = (f32x4){0.f, 0.f, 0.f, 0.f};
                s = __builtin_amdgcn_mfma_f32_16x16x32_bf16(qf[rg][0], kf0, s, 0, 0, 0);
                s = __builtin_amdgcn_mfma_f32_16x16x32_bf16(qf[rg][1], kf1, s, 0, 0, 0);
                #pragma unroll
                for (int j = 0; j < 4; ++j) lsum[rg][j] += __expf(s[j]);
            }
        }
    }
    #pragma unroll
    for (int mask = 1; mask <= 8; mask <<= 1)
        #pragma unroll
        for (int rg = 0; rg < 4; ++rg)
            #pragma unroll
            for (int j = 0; j < 4; ++j)
                lsum[rg][j] += __shfl_xor(lsum[rg][j], mask);
    if (lr == 0)
        #pragma unroll
        for (int rg = 0; rg < 4; ++rg)
            #pragma unroll
            for (int j = 0; j < 4; ++j)
                sum_lds[w * 64 + rg * 16 + lg * 4 + j] = lsum[rg][j];
    __syncthreads();
    float il[4][4];
    #pragma unroll
    for (int rg = 0; rg < 4; ++rg)
        #pragma unroll
        for (int j = 0; j < 4; ++j) {
            int row = rg * 16 + lg * 4 + j;
            il[rg][j] = 1.0f / (sum_lds[row] + sum_lds[64 + row] +
                                sum_lds[128 + row] + sum_lds[192 + row]);
        }

    // ---------------- Phase 2: P write + partial O over this wave's cols ---
    f32x4 oacc[4][4];   // [row-group][d-group], partial over wave's cols
    #pragma unroll
    for (int rg = 0; rg < 4; ++rg)
        #pragma unroll
        for (int nd = 0; nd < 4; ++nd)
            oacc[rg][nd] = (f32x4){0.f, 0.f, 0.f, 0.f};

    for (int t = 0; t < 4; ++t) {
        const int kt = w * 4 + t;
        // scores -> exp*il -> band (64 rows x 128 cols)
        #pragma unroll
        for (int ni = 0; ni < 8; ++ni) {
            const bf16_t* kp = Kp + (size_t)(kt * 8 + ni) * 1024 + lane * 8;
            bf16x8 kf0 = *(const bf16x8*)(kp);
            bf16x8 kf1 = *(const bf16x8*)(kp + 512);
            #pragma unroll
            for (int rg = 0; rg < 4; ++rg) {
                f32x4 s = (f32x4){0.f, 0.f, 0.f, 0.f};
                s = __builtin_amdgcn_mfma_f32_16x16x32_bf16(qf[rg][0], kf0, s, 0, 0, 0);
                s = __builtin_amdgcn_mfma_f32_16x16x32_bf16(qf[rg][1], kf1, s, 0, 0, 0);
                #pragma unroll
                for (int j = 0; j < 4; ++j)
                    Psw[(rg * 16 + lg * 4 + j) * 134 + ni * 16 + lr] =
                        f2b(__expf(s[j]) * il[rg][j]);
            }
        }
        // coalesced P store of the 64x128 stripe (own cols -> no races)
        #pragma unroll
        for (int i = 0; i < 32; ++i) {
            int row = 2 * i + (lane >> 5);
            int col0 = (lane & 31) * 4;
            bf16x4 p4 = *(const bf16x4*)&Psw[row * 134 + col0];
            f32x4 o;
            o[0] = (float)p4[0]; o[1] = (float)p4[1];
            o[2] = (float)p4[2]; o[3] = (float)p4[3];
            *(f32x4*)&Pp[(size_t)row * Sdim + kt * KVB + col0] = o;
        }
        // PV partial accumulate
        #pragma unroll
        for (int ks = 0; ks < 4; ++ks) {
            bf16x8 pa[4];
            #pragma unroll
            for (int rg = 0; rg < 4; ++rg)
                pa[rg] = *(const bf16x8*)&Psw[(rg * 16 + lr) * 134 + ks * 32 + lg * 8];
            #pragma unroll
            for (int nd = 0; nd < 4; ++nd) {
                bf16x8 vf = *(const bf16x8*)(Vp + ((size_t)(kt * 4 + ks) * 4 + nd) * 512 + lane * 8);
                #pragma unroll
                for (int rg = 0; rg < 4; ++rg)
                    oacc[rg][nd] = __builtin_amdgcn_mfma_f32_16x16x32_bf16(
                        pa[rg], vf, oacc[rg][nd], 0, 0, 0);
            }
        }
    }

    // ---------------- O reduction across the 4 waves ----------------
    __syncthreads();   // all waves done reading their bands (aliased w/ red)
    #pragma unroll
    for (int rg = 0; rg < 4; ++rg)
        #pragma unroll
        for (int nd = 0; nd < 4; ++nd)
            #pragma unroll
            for (int j = 0; j < 4; ++j)
                redf[(size_t)w * 4096 + (rg * 16 + lg * 4 + j) * 64 + nd * 16 + lr] =
                    oacc[rg][nd][j];
    __syncthreads();
    #pragma unroll
    for (int i = 0; i < 16; ++i) {
        int row = w * 16 + i;
        int d = lane;
        float s4 = redf[row * 64 + d] + redf[4096 + row * 64 + d] +
                   redf[8192 + row * 64 + d] + redf[12288 + row * 64 + d];
        AOb[((size_t)(b * Sdim + qt * 64 + row)) * Edim + h * Ddim + d] = f2b(s4);
    }
}

// ---- Kernel 3: output = AO @ Wo^T + bo -> d_out f32. Wo pre-converted bf16.
__global__ __launch_bounds__(256) void k_oproj(
    const bf16_t* __restrict__ AOb, const bf16_t* __restrict__ Wob,
    const float* __restrict__ bo, float* __restrict__ out) {
    f32x4 acc[4][4];
    gemm_core<bf16_t, bf16_t, 4>(AOb + (size_t)blockIdx.y * 128 * Edim, Edim,
                                 Wob + (size_t)blockIdx.x * 128 * Edim, Edim, Edim, acc);
    const int tid = threadIdx.x, lane = tid & 63, w = tid >> 6;
    const int wm = w >> 1, wn = w & 1, lr = lane & 15, lg = lane >> 4;
    #pragma unroll
    for (int mi = 0; mi < 4; ++mi)
        #pragma unroll
        for (int ni = 0; ni < 4; ++ni)
            #pragma unroll
            for (int j = 0; j < 4; ++j) {
                int gm = blockIdx.y * 128 + wm * 64 + mi * 16 + lg * 4 + j;
                int gn = blockIdx.x * 128 + wn * 64 + ni * 16 + lr;
                out[(size_t)gm * Edim + gn] = acc[mi][ni][j] + bo[gn];
            }
}

extern "C" void kernel_launch(void* const* d_in, const int* in_sizes, int n_in,
                              void* d_out, int out_size, void* d_ws, size_t ws_size,
                              hipStream_t stream) {
    const float* query = (const float*)d_in[0];
    const float* key_  = (const float*)d_in[1];
    const float* value = (const float*)d_in[2];
    const float* Wq = (const float*)d_in[3];
    const float* bq = (const float*)d_in[4];
    const float* Wk = (const float*)d_in[5];
    const float* bk = (const float*)d_in[6];
    const float* Wv = (const float*)d_in[7];
    const float* bv = (const float*)d_in[8];
    const float* Wo = (const float*)d_in[9];
    const float* bo = (const float*)d_in[10];

    float* out = (float*)d_out;                      // [4096][1024]
    float* P = out + (size_t)MROWS * Edim;           // [32][2048][2048] attn weights

    const size_t WSZ = (size_t)Edim * Edim;                 // 1M elems per W
    const size_t HSD = (size_t)Bdim * Hdim * Sdim * Ddim;   // 4M elems
    bf16_t* Wb   = (bf16_t*)d_ws;       // 4 x [E,E]  (Wq*0.125, Wk, Wv, Wo)
    bf16_t* Qb   = Wb + 4 * WSZ;        // [B,H,S,D]  (pre-scaled)
    bf16_t* Kswz = Qb + HSD;            // fragment-major K
    bf16_t* Vswz = Kswz + HSD;          // fragment-major V
    bf16_t* AOb  = Vswz + HSD;          // [B,S,E]

    k_convert<<<dim3(512, 4), 256, 0, stream>>>(Wq, Wk, Wv, Wo, Wb);
    k_proj<<<dim3(8, 32, 3), 256, 0, stream>>>(query, key_, value, Wb,
                                               bq, bk, bv, Qb, Kswz, Vswz);
    k_attn<<<dim3(1024), 256, 0, stream>>>(Qb, Kswz, Vswz, P, AOb);
    k_oproj<<<dim3(8, 32, 1), 256, 0, stream>>>(AOb, Wb + 3 * WSZ, bo, out);
}

// Round 13
// 447.822 us; speedup vs baseline: 1.2038x; 1.2038x over previous
//
#include <hip/hip_runtime.h>
#include <hip/hip_bf16.h>
#include <cstdint>
#include <cstddef>

#define Bdim 2
#define Sdim 2048
#define Edim 1024
#define Hdim 16
#define Ddim 64
#define KVB 128
#define MROWS (Bdim*Sdim)

typedef __bf16 bf16_t;
typedef __attribute__((ext_vector_type(8))) __bf16 bf16x8;
typedef __attribute__((ext_vector_type(4))) __bf16 bf16x4;
typedef __attribute__((ext_vector_type(4))) float f32x4;

__device__ inline bf16_t f2b(float x) {
    unsigned u = __builtin_bit_cast(unsigned, x);
    unsigned r = u + 0x7fffu + ((u >> 16) & 1u);
    return __builtin_bit_cast(bf16_t, (unsigned short)(r >> 16));
}

// Stage a ROWS x 32 tile (row-major, leading dim ld) into LDS as bf16, rows
// padded to 40 elements. Converts f32 -> bf16 on the fly when T == float.
template<typename T, int ROWS>
__device__ inline void stage_tile(bf16_t* dst, const T* src, int ld, int tid) {
    for (int i = tid; i < ROWS * 4; i += 256) {
        int r = i >> 2;
        int c = (i & 3) * 8;
        const T* s = src + (size_t)r * ld + c;
        bf16x8 v;
        if constexpr (sizeof(T) == 4) {
            const float4* sf = (const float4*)s;
            float4 a = sf[0], b = sf[1];
            v[0] = f2b(a.x); v[1] = f2b(a.y); v[2] = f2b(a.z); v[3] = f2b(a.w);
            v[4] = f2b(b.x); v[5] = f2b(b.y); v[6] = f2b(b.z); v[7] = f2b(b.w);
        } else {
            v = *(const bf16x8*)s;
        }
        *(bf16x8*)(dst + r * 40 + c) = v;
    }
}

// Core: C[128 x BN] += A[128 x K] * B^T, B row-major [BN x K]. 4 waves 2x2.
template<typename TA, typename TB, int FN>
__device__ inline void gemm_core(const TA* A, int lda, const TB* B, int ldb, int K,
                                 f32x4 (&acc)[4][FN]) {
    constexpr int BN = FN * 32;
    __shared__ bf16_t As[128 * 40];
    __shared__ bf16_t Bs[BN * 40];
    const int tid = threadIdx.x;
    const int lane = tid & 63;
    const int w = tid >> 6;
    const int wm = w >> 1, wn = w & 1;
    const int lr = lane & 15, lg = lane >> 4;

    #pragma unroll
    for (int mi = 0; mi < 4; ++mi)
        #pragma unroll
        for (int ni = 0; ni < FN; ++ni)
            acc[mi][ni] = (f32x4){0.f, 0.f, 0.f, 0.f};

    for (int kt = 0; kt < K; kt += 32) {
        __syncthreads();
        stage_tile<TA, 128>(As, A + kt, lda, tid);
        stage_tile<TB, BN>(Bs, B + kt, ldb, tid);
        __syncthreads();
        bf16x8 af[4], bf[FN];
        #pragma unroll
        for (int mi = 0; mi < 4; ++mi)
            af[mi] = *(const bf16x8*)&As[(wm * 64 + mi * 16 + lr) * 40 + lg * 8];
        #pragma unroll
        for (int ni = 0; ni < FN; ++ni)
            bf[ni] = *(const bf16x8*)&Bs[(wn * (FN * 16) + ni * 16 + lr) * 40 + lg * 8];
        #pragma unroll
        for (int mi = 0; mi < 4; ++mi)
            #pragma unroll
            for (int ni = 0; ni < FN; ++ni)
                acc[mi][ni] = __builtin_amdgcn_mfma_f32_16x16x32_bf16(
                    af[mi], bf[ni], acc[mi][ni], 0, 0, 0);
    }
}

// ---- Kernel 0: convert the 4 weight matrices to bf16; Wq scaled by 0.125.
__global__ __launch_bounds__(256) void k_convert(
    const float* __restrict__ Wq, const float* __restrict__ Wk,
    const float* __restrict__ Wv, const float* __restrict__ Wo,
    bf16_t* __restrict__ dst) {
    const int z = blockIdx.y;
    const float* src = (z == 0) ? Wq : (z == 1) ? Wk : (z == 2) ? Wv : Wo;
    const float scale = (z == 0) ? 0.125f : 1.0f;
    bf16_t* d = dst + (size_t)z * Edim * Edim;
    const int i = blockIdx.x * 256 + threadIdx.x;
    const float4* s4 = (const float4*)(src + (size_t)i * 8);
    float4 a = s4[0], b = s4[1];
    bf16x8 v;
    v[0] = f2b(a.x * scale); v[1] = f2b(a.y * scale);
    v[2] = f2b(a.z * scale); v[3] = f2b(a.w * scale);
    v[4] = f2b(b.x * scale); v[5] = f2b(b.y * scale);
    v[6] = f2b(b.z * scale); v[7] = f2b(b.w * scale);
    *(bf16x8*)(d + (size_t)i * 8) = v;
}

// ---- Kernel 1: QKV projections. z = 0/1/2 -> Q/K/V. W pre-converted bf16.
// Q (pre-scaled by 0.125) -> [B,H,S,D]; K,V -> MFMA-fragment-major swizzled:
//   Kswz[bh][s/16][d/8][s%16][d%8]
//   Vswz[bh][s/32][d/16][(s/8)%4][d%16][s%8]
__global__ __launch_bounds__(256) void k_proj(
    const float* __restrict__ xq, const float* __restrict__ xk, const float* __restrict__ xv,
    const bf16_t* __restrict__ Wb,
    const float* __restrict__ bq, const float* __restrict__ bk, const float* __restrict__ bv,
    bf16_t* __restrict__ Qb, bf16_t* __restrict__ Kswz, bf16_t* __restrict__ Vswz) {
    const int z = blockIdx.z;
    const float* X = (z == 0) ? xq : (z == 1) ? xk : xv;
    const bf16_t* W = Wb + (size_t)z * Edim * Edim;
    const float* bias = (z == 0) ? bq : (z == 1) ? bk : bv;
    const float bscale = (z == 0) ? 0.125f : 1.0f;
    const int tm = blockIdx.y, tn = blockIdx.x;
    f32x4 acc[4][4];
    gemm_core<float, bf16_t, 4>(X + (size_t)tm * 128 * Edim, Edim,
                                W + (size_t)tn * 128 * Edim, Edim, Edim, acc);
    const int tid = threadIdx.x, lane = tid & 63, w = tid >> 6;
    const int wm = w >> 1, wn = w & 1, lr = lane & 15, lg = lane >> 4;
    #pragma unroll
    for (int mi = 0; mi < 4; ++mi)
        #pragma unroll
        for (int ni = 0; ni < 4; ++ni)
            #pragma unroll
            for (int j = 0; j < 4; ++j) {
                int gm = tm * 128 + wm * 64 + mi * 16 + lg * 4 + j;
                int gn = tn * 128 + wn * 64 + ni * 16 + lr;
                float v = acc[mi][ni][j] + bias[gn] * bscale;
                int b = gm >> 11, s = gm & (Sdim - 1);
                int h = gn >> 6, d = gn & (Ddim - 1);
                size_t bh = (size_t)(b * Hdim + h);
                if (z == 0) {
                    Qb[(bh * Sdim + s) * Ddim + d] = f2b(v);
                } else if (z == 1) {
                    size_t idx = ((bh * (Sdim / 16) + (s >> 4)) * 8 + (d >> 3)) * 128
                               + (s & 15) * 8 + (d & 7);
                    Kswz[idx] = f2b(v);
                } else {
                    size_t idx = (((bh * (Sdim / 32) + (s >> 5)) * 4 + (d >> 4)) * 4
                               + ((s >> 3) & 3)) * 128 + (d & 15) * 8 + (s & 7);
                    Vswz[idx] = f2b(v);
                }
            }
}

// ---- Kernel 2: fused attention v10 = r9 champion + 2KB-chunk P stores.
// Single variable vs r9: normalized P accumulates in a per-wave LDS buffer
// over 4 k-tiles (16 rows x 512 cols bf16), then flushes 2KB-contiguous per
// row (4x larger HBM write chunks; identical store count & total traffic).
// Theory: 512B-chunk writes at 8KB stride cap HBM write BW at ~1.45 TB/s.
__global__ __launch_bounds__(256) void k_attn(
    const bf16_t* __restrict__ Qb, const bf16_t* __restrict__ Kswz,
    const bf16_t* __restrict__ Vswz, float* __restrict__ P, bf16_t* __restrict__ AOb) {
    const int wg = blockIdx.x;
    const int id = ((wg & 7) << 7) | (wg >> 3);   // bijective XCD swizzle
    const int bh = id >> 5, qt = id & 31;
    const int b = bh >> 4, h = bh & 15;
    const int tid = threadIdx.x, lane = tid & 63, w = tid >> 6;
    const int lr = lane & 15, lg = lane >> 4;

    // Per-wave P accumulation band: 16 rows x 536 (512 used + pad).
    // 536*2B = 1072B row stride: 16B-aligned (b128-safe), bank stride 12
    // -> <=2-way conflicts on all access patterns.
    __shared__ bf16_t Pacc[4][16][536];

    const bf16_t* Qp = Qb + ((size_t)bh * Sdim + qt * 64 + w * 16) * Ddim;
    const bf16_t* Kp = Kswz + (size_t)bh * Sdim * Ddim;
    const bf16_t* Vp = Vswz + (size_t)bh * Ddim * Sdim;
    float* Pp = P + (size_t)bh * Sdim * Sdim + (size_t)(qt * 64 + w * 16) * Sdim;

    // Q fragments (pre-scaled by 1/8 at projection).
    bf16x8 qf[2];
    #pragma unroll
    for (int kk = 0; kk < 2; ++kk)
        qf[kk] = *(const bf16x8*)(Qp + lr * Ddim + kk * 32 + lg * 8);

    // ---------------- Phase 1: row sums of exp(s) ----------------
    float lsum[4] = {0.f, 0.f, 0.f, 0.f};
    for (int kt = 0; kt < Sdim / KVB; ++kt) {
        bf16x8 kf[8][2];
        #pragma unroll
        for (int ni = 0; ni < 8; ++ni) {
            const bf16_t* kp = Kp + (size_t)(kt * 8 + ni) * 1024 + lane * 8;
            kf[ni][0] = *(const bf16x8*)(kp);
            kf[ni][1] = *(const bf16x8*)(kp + 512);
        }
        f32x4 sacc[8];
        #pragma unroll
        for (int ni = 0; ni < 8; ++ni) {
            sacc[ni] = (f32x4){0.f, 0.f, 0.f, 0.f};
            sacc[ni] = __builtin_amdgcn_mfma_f32_16x16x32_bf16(qf[0], kf[ni][0], sacc[ni], 0, 0, 0);
            sacc[ni] = __builtin_amdgcn_mfma_f32_16x16x32_bf16(qf[1], kf[ni][1], sacc[ni], 0, 0, 0);
        }
        #pragma unroll
        for (int ni = 0; ni < 8; ++ni)
            #pragma unroll
            for (int j = 0; j < 4; ++j)
                lsum[j] += __expf(sacc[ni][j]);
    }
    #pragma unroll
    for (int mask = 1; mask <= 8; mask <<= 1)
        #pragma unroll
        for (int j = 0; j < 4; ++j)
            lsum[j] += __shfl_xor(lsum[j], mask);
    float il[4];
    #pragma unroll
    for (int j = 0; j < 4; ++j) il[j] = 1.0f / lsum[j];

    // ---------------- Phase 2: P (4-tile buffered) + O = P.V ----------------
    f32x4 oacc[4];
    #pragma unroll
    for (int nd = 0; nd < 4; ++nd) oacc[nd] = (f32x4){0.f, 0.f, 0.f, 0.f};

    for (int kt = 0; kt < Sdim / KVB; ++kt) {
        const int cb = (kt & 3) * 128;   // column base within Pacc
        bf16x8 kf[8][2];
        #pragma unroll
        for (int ni = 0; ni < 8; ++ni) {
            const bf16_t* kp = Kp + (size_t)(kt * 8 + ni) * 1024 + lane * 8;
            kf[ni][0] = *(const bf16x8*)(kp);
            kf[ni][1] = *(const bf16x8*)(kp + 512);
        }
        bf16x8 vf[4][4];
        #pragma unroll
        for (int ks = 0; ks < 4; ++ks)
            #pragma unroll
            for (int nd = 0; nd < 4; ++nd)
                vf[ks][nd] = *(const bf16x8*)(Vp + ((size_t)(kt * 4 + ks) * 4 + nd) * 512 + lane * 8);
        // scores -> exp*il -> Pacc columns [cb, cb+128)
        #pragma unroll
        for (int ni = 0; ni < 8; ++ni) {
            f32x4 s = (f32x4){0.f, 0.f, 0.f, 0.f};
            s = __builtin_amdgcn_mfma_f32_16x16x32_bf16(qf[0], kf[ni][0], s, 0, 0, 0);
            s = __builtin_amdgcn_mfma_f32_16x16x32_bf16(qf[1], kf[ni][1], s, 0, 0, 0);
            #pragma unroll
            for (int j = 0; j < 4; ++j)
                Pacc[w][lg * 4 + j][cb + ni * 16 + lr] = f2b(__expf(s[j]) * il[j]);
        }
        // PV accumulate from Pacc + vf
        #pragma unroll
        for (int ks = 0; ks < 4; ++ks) {
            bf16x8 pa = *(const bf16x8*)&Pacc[w][lr][cb + ks * 32 + lg * 8];
            #pragma unroll
            for (int nd = 0; nd < 4; ++nd)
                oacc[nd] = __builtin_amdgcn_mfma_f32_16x16x32_bf16(pa, vf[ks][nd], oacc[nd], 0, 0, 0);
        }
        // every 4th tile: flush 16 rows x 512 cols as 2KB-contiguous rows
        if ((kt & 3) == 3) {
            const int c4 = (kt >> 2) * 512;
            #pragma unroll
            for (int r = 0; r < 16; ++r)
                #pragma unroll
                for (int i = 0; i < 2; ++i) {
                    bf16x4 p4 = *(const bf16x4*)&Pacc[w][r][i * 256 + lane * 4];
                    f32x4 o;
                    o[0] = (float)p4[0]; o[1] = (float)p4[1];
                    o[2] = (float)p4[2]; o[3] = (float)p4[3];
                    *(f32x4*)&Pp[(size_t)r * Sdim + c4 + i * 256 + lane * 4] = o;
                }
        }
    }

    // epilogue: AO bf16 [B,S,E]
    #pragma unroll
    for (int nd = 0; nd < 4; ++nd)
        #pragma unroll
        for (int j = 0; j < 4; ++j) {
            int s = qt * 64 + w * 16 + lg * 4 + j;
            int d = nd * 16 + lr;
            AOb[((size_t)(b * Sdim + s)) * Edim + h * Ddim + d] = f2b(oacc[nd][j]);
        }
}

// ---- Kernel 3: output = AO @ Wo^T + bo -> d_out f32. Wo pre-converted bf16.
__global__ __launch_bounds__(256) void k_oproj(
    const bf16_t* __restrict__ AOb, const bf16_t* __restrict__ Wob,
    const float* __restrict__ bo, float* __restrict__ out) {
    f32x4 acc[4][4];
    gemm_core<bf16_t, bf16_t, 4>(AOb + (size_t)blockIdx.y * 128 * Edim, Edim,
                                 Wob + (size_t)blockIdx.x * 128 * Edim, Edim, Edim, acc);
    const int tid = threadIdx.x, lane = tid & 63, w = tid >> 6;
    const int wm = w >> 1, wn = w & 1, lr = lane & 15, lg = lane >> 4;
    #pragma unroll
    for (int mi = 0; mi < 4; ++mi)
        #pragma unroll
        for (int ni = 0; ni < 4; ++ni)
            #pragma unroll
            for (int j = 0; j < 4; ++j) {
                int gm = blockIdx.y * 128 + wm * 64 + mi * 16 + lg * 4 + j;
                int gn = blockIdx.x * 128 + wn * 64 + ni * 16 + lr;
                out[(size_t)gm * Edim + gn] = acc[mi][ni][j] + bo[gn];
            }
}

extern "C" void kernel_launch(void* const* d_in, const int* in_sizes, int n_in,
                              void* d_out, int out_size, void* d_ws, size_t ws_size,
                              hipStream_t stream) {
    const float* query = (const float*)d_in[0];
    const float* key_  = (const float*)d_in[1];
    const float* value = (const float*)d_in[2];
    const float* Wq = (const float*)d_in[3];
    const float* bq = (const float*)d_in[4];
    const float* Wk = (const float*)d_in[5];
    const float* bk = (const float*)d_in[6];
    const float* Wv = (const float*)d_in[7];
    const float* bv = (const float*)d_in[8];
    const float* Wo = (const float*)d_in[9];
    const float* bo = (const float*)d_in[10];

    float* out = (float*)d_out;                      // [4096][1024]
    float* P = out + (size_t)MROWS * Edim;           // [32][2048][2048] attn weights

    const size_t WSZ = (size_t)Edim * Edim;                 // 1M elems per W
    const size_t HSD = (size_t)Bdim * Hdim * Sdim * Ddim;   // 4M elems
    bf16_t* Wb   = (bf16_t*)d_ws;       // 4 x [E,E]  (Wq*0.125, Wk, Wv, Wo)
    bf16_t* Qb   = Wb + 4 * WSZ;        // [B,H,S,D]  (pre-scaled)
    bf16_t* Kswz = Qb + HSD;            // fragment-major K
    bf16_t* Vswz = Kswz + HSD;          // fragment-major V
    bf16_t* AOb  = Vswz + HSD;          // [B,S,E]

    k_convert<<<dim3(512, 4), 256, 0, stream>>>(Wq, Wk, Wv, Wo, Wb);
    k_proj<<<dim3(8, 32, 3), 256, 0, stream>>>(query, key_, value, Wb,
                                               bq, bk, bv, Qb, Kswz, Vswz);
    k_attn<<<dim3(1024), 256, 0, stream>>>(Qb, Kswz, Vswz, P, AOb);
    k_oproj<<<dim3(8, 32, 1), 256, 0, stream>>>(AOb, Wb + 3 * WSZ, bo, out);
}

// Round 14
// 355.295 us; speedup vs baseline: 1.5173x; 1.2604x over previous
//
#include <hip/hip_runtime.h>
#include <hip/hip_bf16.h>
#include <cstdint>
#include <cstddef>

#define Bdim 2
#define Sdim 2048
#define Edim 1024
#define Hdim 16
#define Ddim 64
#define KVB 128
#define MROWS (Bdim*Sdim)

typedef __bf16 bf16_t;
typedef __attribute__((ext_vector_type(8))) __bf16 bf16x8;
typedef __attribute__((ext_vector_type(4))) __bf16 bf16x4;
typedef __attribute__((ext_vector_type(4))) float f32x4;

__device__ inline bf16_t f2b(float x) {
    unsigned u = __builtin_bit_cast(unsigned, x);
    unsigned r = u + 0x7fffu + ((u >> 16) & 1u);
    return __builtin_bit_cast(bf16_t, (unsigned short)(r >> 16));
}

// Stage a ROWS x 32 tile (row-major, leading dim ld) into LDS as bf16, rows
// padded to 40 elements.
template<typename T, int ROWS>
__device__ inline void stage_tile(bf16_t* dst, const T* src, int ld, int tid) {
    for (int i = tid; i < ROWS * 4; i += 256) {
        int r = i >> 2;
        int c = (i & 3) * 8;
        const T* s = src + (size_t)r * ld + c;
        bf16x8 v;
        if constexpr (sizeof(T) == 4) {
            const float4* sf = (const float4*)s;
            float4 a = sf[0], b = sf[1];
            v[0] = f2b(a.x); v[1] = f2b(a.y); v[2] = f2b(a.z); v[3] = f2b(a.w);
            v[4] = f2b(b.x); v[5] = f2b(b.y); v[6] = f2b(b.z); v[7] = f2b(b.w);
        } else {
            v = *(const bf16x8*)s;
        }
        *(bf16x8*)(dst + r * 40 + c) = v;
    }
}

// Core: C[128 x BN] += A[128 x K] * B^T, B row-major [BN x K]. 4 waves 2x2.
template<typename TA, typename TB, int FN>
__device__ inline void gemm_core(const TA* A, int lda, const TB* B, int ldb, int K,
                                 f32x4 (&acc)[4][FN]) {
    constexpr int BN = FN * 32;
    __shared__ bf16_t As[128 * 40];
    __shared__ bf16_t Bs[BN * 40];
    const int tid = threadIdx.x;
    const int lane = tid & 63;
    const int w = tid >> 6;
    const int wm = w >> 1, wn = w & 1;
    const int lr = lane & 15, lg = lane >> 4;

    #pragma unroll
    for (int mi = 0; mi < 4; ++mi)
        #pragma unroll
        for (int ni = 0; ni < FN; ++ni)
            acc[mi][ni] = (f32x4){0.f, 0.f, 0.f, 0.f};

    for (int kt = 0; kt < K; kt += 32) {
        __syncthreads();
        stage_tile<TA, 128>(As, A + kt, lda, tid);
        stage_tile<TB, BN>(Bs, B + kt, ldb, tid);
        __syncthreads();
        bf16x8 af[4], bf[FN];
        #pragma unroll
        for (int mi = 0; mi < 4; ++mi)
            af[mi] = *(const bf16x8*)&As[(wm * 64 + mi * 16 + lr) * 40 + lg * 8];
        #pragma unroll
        for (int ni = 0; ni < FN; ++ni)
            bf[ni] = *(const bf16x8*)&Bs[(wn * (FN * 16) + ni * 16 + lr) * 40 + lg * 8];
        #pragma unroll
        for (int mi = 0; mi < 4; ++mi)
            #pragma unroll
            for (int ni = 0; ni < FN; ++ni)
                acc[mi][ni] = __builtin_amdgcn_mfma_f32_16x16x32_bf16(
                    af[mi], bf[ni], acc[mi][ni], 0, 0, 0);
    }
}

// ---- Kernel 0: convert weights AND the 3 input activations to bf16.
// z 0..3: Wq*0.125, Wk, Wv, Wo (1M elems each; blocks >= 512 idle).
// z 4..6: query/key_/value -> Xb (4M elems each).
__global__ __launch_bounds__(256) void k_convert(
    const float* __restrict__ Wq, const float* __restrict__ Wk,
    const float* __restrict__ Wv, const float* __restrict__ Wo,
    const float* __restrict__ xq, const float* __restrict__ xk,
    const float* __restrict__ xv,
    bf16_t* __restrict__ Wb, bf16_t* __restrict__ Xb) {
    const int z = blockIdx.y;
    const float* src;
    bf16_t* d;
    float scale = 1.0f;
    if (z < 4) {
        if (blockIdx.x >= 512) return;
        src = (z == 0) ? Wq : (z == 1) ? Wk : (z == 2) ? Wv : Wo;
        scale = (z == 0) ? 0.125f : 1.0f;
        d = Wb + (size_t)z * Edim * Edim;
    } else {
        src = (z == 4) ? xq : (z == 5) ? xk : xv;
        d = Xb + (size_t)(z - 4) * MROWS * Edim;
    }
    const size_t i = (size_t)blockIdx.x * 256 + threadIdx.x;
    const float4* s4 = (const float4*)(src + i * 8);
    float4 a = s4[0], b = s4[1];
    bf16x8 v;
    v[0] = f2b(a.x * scale); v[1] = f2b(a.y * scale);
    v[2] = f2b(a.z * scale); v[3] = f2b(a.w * scale);
    v[4] = f2b(b.x * scale); v[5] = f2b(b.y * scale);
    v[6] = f2b(b.z * scale); v[7] = f2b(b.w * scale);
    *(bf16x8*)(d + i * 8) = v;
}

// ---- Kernel 1: QKV projections, all-bf16 GEMM (A pre-converted).
// Q (pre-scaled by 0.125) -> [B,H,S,D]; K,V -> MFMA-fragment-major swizzled:
//   Kswz[bh][s/16][d/8][s%16][d%8]
//   Vswz[bh][s/32][d/16][(s/8)%4][d%16][s%8]
__global__ __launch_bounds__(256) void k_proj(
    const bf16_t* __restrict__ Xb, const bf16_t* __restrict__ Wb,
    const float* __restrict__ bq, const float* __restrict__ bk, const float* __restrict__ bv,
    bf16_t* __restrict__ Qb, bf16_t* __restrict__ Kswz, bf16_t* __restrict__ Vswz) {
    const int z = blockIdx.z;
    const bf16_t* X = Xb + (size_t)z * MROWS * Edim;
    const bf16_t* W = Wb + (size_t)z * Edim * Edim;
    const float* bias = (z == 0) ? bq : (z == 1) ? bk : bv;
    const float bscale = (z == 0) ? 0.125f : 1.0f;
    const int tm = blockIdx.y, tn = blockIdx.x;
    f32x4 acc[4][4];
    gemm_core<bf16_t, bf16_t, 4>(X + (size_t)tm * 128 * Edim, Edim,
                                 W + (size_t)tn * 128 * Edim, Edim, Edim, acc);
    const int tid = threadIdx.x, lane = tid & 63, w = tid >> 6;
    const int wm = w >> 1, wn = w & 1, lr = lane & 15, lg = lane >> 4;
    #pragma unroll
    for (int mi = 0; mi < 4; ++mi)
        #pragma unroll
        for (int ni = 0; ni < 4; ++ni)
            #pragma unroll
            for (int j = 0; j < 4; ++j) {
                int gm = tm * 128 + wm * 64 + mi * 16 + lg * 4 + j;
                int gn = tn * 128 + wn * 64 + ni * 16 + lr;
                float v = acc[mi][ni][j] + bias[gn] * bscale;
                int b = gm >> 11, s = gm & (Sdim - 1);
                int h = gn >> 6, d = gn & (Ddim - 1);
                size_t bh = (size_t)(b * Hdim + h);
                if (z == 0) {
                    Qb[(bh * Sdim + s) * Ddim + d] = f2b(v);
                } else if (z == 1) {
                    size_t idx = ((bh * (Sdim / 16) + (s >> 4)) * 8 + (d >> 3)) * 128
                               + (s & 15) * 8 + (d & 7);
                    Kswz[idx] = f2b(v);
                } else {
                    size_t idx = (((bh * (Sdim / 32) + (s >> 5)) * 4 + (d >> 4)) * 4
                               + ((s >> 3) & 3)) * 128 + (d & 15) * 8 + (s & 7);
                    Vswz[idx] = f2b(v);
                }
            }
}

// ---- Kernel 2: fused attention (r9 champion, verbatim).
// Fragment-contiguous K/V loads; issue loads before prev-tile P stores;
// double-buffered LDS P bands; coalesced f32x4 P stores.
__global__ __launch_bounds__(256) void k_attn(
    const bf16_t* __restrict__ Qb, const bf16_t* __restrict__ Kswz,
    const bf16_t* __restrict__ Vswz, float* __restrict__ P, bf16_t* __restrict__ AOb) {
    const int wg = blockIdx.x;
    const int id = ((wg & 7) << 7) | (wg >> 3);   // bijective XCD swizzle
    const int bh = id >> 5, qt = id & 31;
    const int b = bh >> 4, h = bh & 15;
    const int tid = threadIdx.x, lane = tid & 63, w = tid >> 6;
    const int lr = lane & 15, lg = lane >> 4;

    __shared__ bf16_t Ps[2][4][16][132];   // double-buffered per-wave P bands

    const bf16_t* Qp = Qb + ((size_t)bh * Sdim + qt * 64 + w * 16) * Ddim;
    const bf16_t* Kp = Kswz + (size_t)bh * Sdim * Ddim;   // fragment-major
    const bf16_t* Vp = Vswz + (size_t)bh * Ddim * Sdim;   // fragment-major
    float* Pp = P + (size_t)bh * Sdim * Sdim + (size_t)(qt * 64 + w * 16) * Sdim;

    bf16x8 qf[2];
    #pragma unroll
    for (int kk = 0; kk < 2; ++kk)
        qf[kk] = *(const bf16x8*)(Qp + lr * Ddim + kk * 32 + lg * 8);

    // ---------------- Phase 1: row sums of exp(s) ----------------
    float lsum[4] = {0.f, 0.f, 0.f, 0.f};
    for (int kt = 0; kt < Sdim / KVB; ++kt) {
        bf16x8 kf[8][2];
        #pragma unroll
        for (int ni = 0; ni < 8; ++ni) {
            const bf16_t* kp = Kp + (size_t)(kt * 8 + ni) * 1024 + lane * 8;
            kf[ni][0] = *(const bf16x8*)(kp);
            kf[ni][1] = *(const bf16x8*)(kp + 512);
        }
        f32x4 sacc[8];
        #pragma unroll
        for (int ni = 0; ni < 8; ++ni) {
            sacc[ni] = (f32x4){0.f, 0.f, 0.f, 0.f};
            sacc[ni] = __builtin_amdgcn_mfma_f32_16x16x32_bf16(qf[0], kf[ni][0], sacc[ni], 0, 0, 0);
            sacc[ni] = __builtin_amdgcn_mfma_f32_16x16x32_bf16(qf[1], kf[ni][1], sacc[ni], 0, 0, 0);
        }
        #pragma unroll
        for (int ni = 0; ni < 8; ++ni)
            #pragma unroll
            for (int j = 0; j < 4; ++j)
                lsum[j] += __expf(sacc[ni][j]);
    }
    #pragma unroll
    for (int mask = 1; mask <= 8; mask <<= 1)
        #pragma unroll
        for (int j = 0; j < 4; ++j)
            lsum[j] += __shfl_xor(lsum[j], mask);
    float il[4];
    #pragma unroll
    for (int j = 0; j < 4; ++j) il[j] = 1.0f / lsum[j];

    // ---------------- Phase 2: pipelined P store + O = P.V ----------------
    f32x4 oacc[4];
    #pragma unroll
    for (int nd = 0; nd < 4; ++nd) oacc[nd] = (f32x4){0.f, 0.f, 0.f, 0.f};

    for (int kt = 0; kt < Sdim / KVB; ++kt) {
        const int cur = kt & 1, prev = cur ^ 1;
        bf16x8 kf[8][2];
        #pragma unroll
        for (int ni = 0; ni < 8; ++ni) {
            const bf16_t* kp = Kp + (size_t)(kt * 8 + ni) * 1024 + lane * 8;
            kf[ni][0] = *(const bf16x8*)(kp);
            kf[ni][1] = *(const bf16x8*)(kp + 512);
        }
        bf16x8 vf[4][4];
        #pragma unroll
        for (int ks = 0; ks < 4; ++ks)
            #pragma unroll
            for (int nd = 0; nd < 4; ++nd)
                vf[ks][nd] = *(const bf16x8*)(Vp + ((size_t)(kt * 4 + ks) * 4 + nd) * 512 + lane * 8);
        if (kt > 0) {
            #pragma unroll
            for (int i = 0; i < 8; ++i) {
                int row = 2 * i + (lane >> 5);
                int col0 = (lane & 31) * 4;
                bf16x4 p4 = *(const bf16x4*)&Ps[prev][w][row][col0];
                f32x4 o;
                o[0] = (float)p4[0]; o[1] = (float)p4[1];
                o[2] = (float)p4[2]; o[3] = (float)p4[3];
                *(f32x4*)&Pp[(size_t)row * Sdim + (kt - 1) * KVB + col0] = o;
            }
        }
        #pragma unroll
        for (int ni = 0; ni < 8; ++ni) {
            f32x4 s = (f32x4){0.f, 0.f, 0.f, 0.f};
            s = __builtin_amdgcn_mfma_f32_16x16x32_bf16(qf[0], kf[ni][0], s, 0, 0, 0);
            s = __builtin_amdgcn_mfma_f32_16x16x32_bf16(qf[1], kf[ni][1], s, 0, 0, 0);
            #pragma unroll
            for (int j = 0; j < 4; ++j)
                Ps[cur][w][lg * 4 + j][ni * 16 + lr] = f2b(__expf(s[j]) * il[j]);
        }
        #pragma unroll
        for (int ks = 0; ks < 4; ++ks) {
            bf16x8 pa = *(const bf16x8*)&Ps[cur][w][lr][ks * 32 + lg * 8];
            #pragma unroll
            for (int nd = 0; nd < 4; ++nd)
                oacc[nd] = __builtin_amdgcn_mfma_f32_16x16x32_bf16(pa, vf[ks][nd], oacc[nd], 0, 0, 0);
        }
    }
    // epilogue: store last tile's band (band index 15&1 = 1)
    #pragma unroll
    for (int i = 0; i < 8; ++i) {
        int row = 2 * i + (lane >> 5);
        int col0 = (lane & 31) * 4;
        bf16x4 p4 = *(const bf16x4*)&Ps[1][w][row][col0];
        f32x4 o;
        o[0] = (float)p4[0]; o[1] = (float)p4[1];
        o[2] = (float)p4[2]; o[3] = (float)p4[3];
        *(f32x4*)&Pp[(size_t)row * Sdim + (Sdim - KVB) + col0] = o;
    }

    // epilogue: AO bf16 [B,S,E]
    #pragma unroll
    for (int nd = 0; nd < 4; ++nd)
        #pragma unroll
        for (int j = 0; j < 4; ++j) {
            int s = qt * 64 + w * 16 + lg * 4 + j;
            int d = nd * 16 + lr;
            AOb[((size_t)(b * Sdim + s)) * Edim + h * Ddim + d] = f2b(oacc[nd][j]);
        }
}

// ---- Kernel 3: output = AO @ Wo^T + bo -> d_out f32. Wo pre-converted bf16.
__global__ __launch_bounds__(256) void k_oproj(
    const bf16_t* __restrict__ AOb, const bf16_t* __restrict__ Wob,
    const float* __restrict__ bo, float* __restrict__ out) {
    f32x4 acc[4][4];
    gemm_core<bf16_t, bf16_t, 4>(AOb + (size_t)blockIdx.y * 128 * Edim, Edim,
                                 Wob + (size_t)blockIdx.x * 128 * Edim, Edim, Edim, acc);
    const int tid = threadIdx.x, lane = tid & 63, w = tid >> 6;
    const int wm = w >> 1, wn = w & 1, lr = lane & 15, lg = lane >> 4;
    #pragma unroll
    for (int mi = 0; mi < 4; ++mi)
        #pragma unroll
        for (int ni = 0; ni < 4; ++ni)
            #pragma unroll
            for (int j = 0; j < 4; ++j) {
                int gm = blockIdx.y * 128 + wm * 64 + mi * 16 + lg * 4 + j;
                int gn = blockIdx.x * 128 + wn * 64 + ni * 16 + lr;
                out[(size_t)gm * Edim + gn] = acc[mi][ni][j] + bo[gn];
            }
}

extern "C" void kernel_launch(void* const* d_in, const int* in_sizes, int n_in,
                              void* d_out, int out_size, void* d_ws, size_t ws_size,
                              hipStream_t stream) {
    const float* query = (const float*)d_in[0];
    const float* key_  = (const float*)d_in[1];
    const float* value = (const float*)d_in[2];
    const float* Wq = (const float*)d_in[3];
    const float* bq = (const float*)d_in[4];
    const float* Wk = (const float*)d_in[5];
    const float* bk = (const float*)d_in[6];
    const float* Wv = (const float*)d_in[7];
    const float* bv = (const float*)d_in[8];
    const float* Wo = (const float*)d_in[9];
    const float* bo = (const float*)d_in[10];

    float* out = (float*)d_out;                      // [4096][1024]
    float* P = out + (size_t)MROWS * Edim;           // [32][2048][2048] attn weights
    const size_t PSZ = (size_t)32 * Sdim * Sdim;     // 134217728 floats

    const size_t WSZ = (size_t)Edim * Edim;                 // 1M elems per W
    const size_t HSD = (size_t)Bdim * Hdim * Sdim * Ddim;   // 4M elems
    bf16_t* Wb   = (bf16_t*)d_ws;       // 4 x [E,E]  (Wq*0.125, Wk, Wv, Wo)
    bf16_t* Qb   = Wb + 4 * WSZ;        // [B,H,S,D]  (pre-scaled)
    bf16_t* Kswz = Qb + HSD;            // fragment-major K
    bf16_t* Vswz = Kswz + HSD;          // fragment-major V
    bf16_t* AOb  = Vswz + HSD;          // [B,S,E]
    // Xb scratch lives in the TAIL of the P region (24MB of its last 48MB);
    // k_proj consumes it before k_attn overwrites all of P.
    bf16_t* Xb   = (bf16_t*)(P + PSZ - 6 * 1024 * 1024);

    k_convert<<<dim3(2048, 7), 256, 0, stream>>>(Wq, Wk, Wv, Wo, query, key_, value,
                                                 Wb, Xb);
    k_proj<<<dim3(8, 32, 3), 256, 0, stream>>>(Xb, Wb, bq, bk, bv, Qb, Kswz, Vswz);
    k_attn<<<dim3(1024), 256, 0, stream>>>(Qb, Kswz, Vswz, P, AOb);
    k_oproj<<<dim3(8, 32, 1), 256, 0, stream>>>(AOb, Wb + 3 * WSZ, bo, out);
}

// Round 15
// 301.949 us; speedup vs baseline: 1.7854x; 1.1767x over previous
//
#include <hip/hip_runtime.h>
#include <hip/hip_bf16.h>
#include <cstdint>
#include <cstddef>

#define Bdim 2
#define Sdim 2048
#define Edim 1024
#define Hdim 16
#define Ddim 64
#define KVB 128
#define MROWS (Bdim*Sdim)

typedef __bf16 bf16_t;
typedef __attribute__((ext_vector_type(8))) __bf16 bf16x8;
typedef __attribute__((ext_vector_type(4))) __bf16 bf16x4;
typedef __attribute__((ext_vector_type(4))) float f32x4;

typedef __attribute__((address_space(3))) uint8_t lds8_t;
typedef const __attribute__((address_space(1))) uint8_t glb8_t;

__device__ inline bf16_t f2b(float x) {
    unsigned u = __builtin_bit_cast(unsigned, x);
    unsigned r = u + 0x7fffu + ((u >> 16) & 1u);
    return __builtin_bit_cast(bf16_t, (unsigned short)(r >> 16));
}

// m97-class bf16 GEMM core: C[128x128] = A[128xK] * B^T (B row-major [128-col
// band][K]). 4 waves 2x2, 16x16x32 MFMA, 4x4 frags/wave. Staging via
// global_load_lds width=16 into LINEAR LDS [128][32] bf16 (no padding; chunk
// base wave-uniform; lane's global addr arranged so base+lane*16 is correct).
__device__ inline void gemm_async(const bf16_t* A, const bf16_t* B, int K,
                                  f32x4 (&acc)[4][4]) {
    __shared__ __align__(16) bf16_t As[128 * 32];
    __shared__ __align__(16) bf16_t Bs[128 * 32];
    const int tid = threadIdx.x;
    const int lane = tid & 63;
    const int w = tid >> 6;
    const int wm = w >> 1, wn = w & 1;
    const int lr = lane & 15, lg = lane >> 4;

    #pragma unroll
    for (int mi = 0; mi < 4; ++mi)
        #pragma unroll
        for (int ni = 0; ni < 4; ++ni)
            acc[mi][ni] = (f32x4){0.f, 0.f, 0.f, 0.f};

    // per-wave staging geometry: chunk c covers rows [c*16, c*16+16) x 32 cols
    // = 1KB; lane l -> row c*16 + l/4, col (l%4)*8  (LDS off = c*1024 + l*16 B)
    const int srow = (lane >> 2);
    const int scol = (lane & 3) * 8;

    for (int kt = 0; kt < K; kt += 32) {
        __syncthreads();
        #pragma unroll
        for (int i = 0; i < 2; ++i) {
            const int chunk = w * 2 + i;
            const int row = chunk * 16 + srow;
            __builtin_amdgcn_global_load_lds(
                (glb8_t*)(A + (size_t)row * K + kt + scol),
                (lds8_t*)(As + chunk * 512), 16, 0, 0);
            __builtin_amdgcn_global_load_lds(
                (glb8_t*)(B + (size_t)row * K + kt + scol),
                (lds8_t*)(Bs + chunk * 512), 16, 0, 0);
        }
        __syncthreads();   // compiler emits vmcnt(0) drain before s_barrier
        bf16x8 af[4], bf[4];
        #pragma unroll
        for (int mi = 0; mi < 4; ++mi)
            af[mi] = *(const bf16x8*)&As[(wm * 64 + mi * 16 + lr) * 32 + lg * 8];
        #pragma unroll
        for (int ni = 0; ni < 4; ++ni)
            bf[ni] = *(const bf16x8*)&Bs[(wn * 64 + ni * 16 + lr) * 32 + lg * 8];
        #pragma unroll
        for (int mi = 0; mi < 4; ++mi)
            #pragma unroll
            for (int ni = 0; ni < 4; ++ni)
                acc[mi][ni] = __builtin_amdgcn_mfma_f32_16x16x32_bf16(
                    af[mi], bf[ni], acc[mi][ni], 0, 0, 0);
    }
}

// ---- Kernel 0: convert weights AND the 3 input activations to bf16.
// z 0..3: Wq*0.125, Wk, Wv, Wo (1M elems each; blocks >= 512 idle).
// z 4..6: query/key_/value -> Xb (4M elems each).
__global__ __launch_bounds__(256) void k_convert(
    const float* __restrict__ Wq, const float* __restrict__ Wk,
    const float* __restrict__ Wv, const float* __restrict__ Wo,
    const float* __restrict__ xq, const float* __restrict__ xk,
    const float* __restrict__ xv,
    bf16_t* __restrict__ Wb, bf16_t* __restrict__ Xb) {
    const int z = blockIdx.y;
    const float* src;
    bf16_t* d;
    float scale = 1.0f;
    if (z < 4) {
        if (blockIdx.x >= 512) return;
        src = (z == 0) ? Wq : (z == 1) ? Wk : (z == 2) ? Wv : Wo;
        scale = (z == 0) ? 0.125f : 1.0f;
        d = Wb + (size_t)z * Edim * Edim;
    } else {
        src = (z == 4) ? xq : (z == 5) ? xk : xv;
        d = Xb + (size_t)(z - 4) * MROWS * Edim;
    }
    const size_t i = (size_t)blockIdx.x * 256 + threadIdx.x;
    const float4* s4 = (const float4*)(src + i * 8);
    float4 a = s4[0], b = s4[1];
    bf16x8 v;
    v[0] = f2b(a.x * scale); v[1] = f2b(a.y * scale);
    v[2] = f2b(a.z * scale); v[3] = f2b(a.w * scale);
    v[4] = f2b(b.x * scale); v[5] = f2b(b.y * scale);
    v[6] = f2b(b.z * scale); v[7] = f2b(b.w * scale);
    *(bf16x8*)(d + i * 8) = v;
}

// ---- Kernel 1: QKV projections, m97-class bf16 GEMM.
// Q (pre-scaled by 0.125) -> [B,H,S,D]; K,V -> MFMA-fragment-major swizzled:
//   Kswz[bh][s/16][d/8][s%16][d%8]
//   Vswz[bh][s/32][d/16][(s/8)%4][d%16][s%8]
__global__ __launch_bounds__(256) void k_proj(
    const bf16_t* __restrict__ Xb, const bf16_t* __restrict__ Wb,
    const float* __restrict__ bq, const float* __restrict__ bk, const float* __restrict__ bv,
    bf16_t* __restrict__ Qb, bf16_t* __restrict__ Kswz, bf16_t* __restrict__ Vswz) {
    const int z = blockIdx.z;
    const bf16_t* X = Xb + (size_t)z * MROWS * Edim;
    const bf16_t* W = Wb + (size_t)z * Edim * Edim;
    const float* bias = (z == 0) ? bq : (z == 1) ? bk : bv;
    const float bscale = (z == 0) ? 0.125f : 1.0f;
    const int tm = blockIdx.y, tn = blockIdx.x;
    f32x4 acc[4][4];
    gemm_async(X + (size_t)tm * 128 * Edim, W + (size_t)tn * 128 * Edim, Edim, acc);
    const int tid = threadIdx.x, lane = tid & 63, w = tid >> 6;
    const int wm = w >> 1, wn = w & 1, lr = lane & 15, lg = lane >> 4;
    #pragma unroll
    for (int mi = 0; mi < 4; ++mi)
        #pragma unroll
        for (int ni = 0; ni < 4; ++ni)
            #pragma unroll
            for (int j = 0; j < 4; ++j) {
                int gm = tm * 128 + wm * 64 + mi * 16 + lg * 4 + j;
                int gn = tn * 128 + wn * 64 + ni * 16 + lr;
                float v = acc[mi][ni][j] + bias[gn] * bscale;
                int b = gm >> 11, s = gm & (Sdim - 1);
                int h = gn >> 6, d = gn & (Ddim - 1);
                size_t bh = (size_t)(b * Hdim + h);
                if (z == 0) {
                    Qb[(bh * Sdim + s) * Ddim + d] = f2b(v);
                } else if (z == 1) {
                    size_t idx = ((bh * (Sdim / 16) + (s >> 4)) * 8 + (d >> 3)) * 128
                               + (s & 15) * 8 + (d & 7);
                    Kswz[idx] = f2b(v);
                } else {
                    size_t idx = (((bh * (Sdim / 32) + (s >> 5)) * 4 + (d >> 4)) * 4
                               + ((s >> 3) & 3)) * 128 + (d & 15) * 8 + (s & 7);
                    Vswz[idx] = f2b(v);
                }
            }
}

// ---- Kernel 2: fused attention (r9 champion, verbatim).
// Fragment-contiguous K/V loads; issue loads before prev-tile P stores;
// double-buffered LDS P bands; coalesced f32x4 P stores.
__global__ __launch_bounds__(256) void k_attn(
    const bf16_t* __restrict__ Qb, const bf16_t* __restrict__ Kswz,
    const bf16_t* __restrict__ Vswz, float* __restrict__ P, bf16_t* __restrict__ AOb) {
    const int wg = blockIdx.x;
    const int id = ((wg & 7) << 7) | (wg >> 3);   // bijective XCD swizzle
    const int bh = id >> 5, qt = id & 31;
    const int b = bh >> 4, h = bh & 15;
    const int tid = threadIdx.x, lane = tid & 63, w = tid >> 6;
    const int lr = lane & 15, lg = lane >> 4;

    __shared__ bf16_t Ps[2][4][16][132];   // double-buffered per-wave P bands

    const bf16_t* Qp = Qb + ((size_t)bh * Sdim + qt * 64 + w * 16) * Ddim;
    const bf16_t* Kp = Kswz + (size_t)bh * Sdim * Ddim;   // fragment-major
    const bf16_t* Vp = Vswz + (size_t)bh * Ddim * Sdim;   // fragment-major
    float* Pp = P + (size_t)bh * Sdim * Sdim + (size_t)(qt * 64 + w * 16) * Sdim;

    bf16x8 qf[2];
    #pragma unroll
    for (int kk = 0; kk < 2; ++kk)
        qf[kk] = *(const bf16x8*)(Qp + lr * Ddim + kk * 32 + lg * 8);

    // ---------------- Phase 1: row sums of exp(s) ----------------
    float lsum[4] = {0.f, 0.f, 0.f, 0.f};
    for (int kt = 0; kt < Sdim / KVB; ++kt) {
        bf16x8 kf[8][2];
        #pragma unroll
        for (int ni = 0; ni < 8; ++ni) {
            const bf16_t* kp = Kp + (size_t)(kt * 8 + ni) * 1024 + lane * 8;
            kf[ni][0] = *(const bf16x8*)(kp);
            kf[ni][1] = *(const bf16x8*)(kp + 512);
        }
        f32x4 sacc[8];
        #pragma unroll
        for (int ni = 0; ni < 8; ++ni) {
            sacc[ni] = (f32x4){0.f, 0.f, 0.f, 0.f};
            sacc[ni] = __builtin_amdgcn_mfma_f32_16x16x32_bf16(qf[0], kf[ni][0], sacc[ni], 0, 0, 0);
            sacc[ni] = __builtin_amdgcn_mfma_f32_16x16x32_bf16(qf[1], kf[ni][1], sacc[ni], 0, 0, 0);
        }
        #pragma unroll
        for (int ni = 0; ni < 8; ++ni)
            #pragma unroll
            for (int j = 0; j < 4; ++j)
                lsum[j] += __expf(sacc[ni][j]);
    }
    #pragma unroll
    for (int mask = 1; mask <= 8; mask <<= 1)
        #pragma unroll
        for (int j = 0; j < 4; ++j)
            lsum[j] += __shfl_xor(lsum[j], mask);
    float il[4];
    #pragma unroll
    for (int j = 0; j < 4; ++j) il[j] = 1.0f / lsum[j];

    // ---------------- Phase 2: pipelined P store + O = P.V ----------------
    f32x4 oacc[4];
    #pragma unroll
    for (int nd = 0; nd < 4; ++nd) oacc[nd] = (f32x4){0.f, 0.f, 0.f, 0.f};

    for (int kt = 0; kt < Sdim / KVB; ++kt) {
        const int cur = kt & 1, prev = cur ^ 1;
        bf16x8 kf[8][2];
        #pragma unroll
        for (int ni = 0; ni < 8; ++ni) {
            const bf16_t* kp = Kp + (size_t)(kt * 8 + ni) * 1024 + lane * 8;
            kf[ni][0] = *(const bf16x8*)(kp);
            kf[ni][1] = *(const bf16x8*)(kp + 512);
        }
        bf16x8 vf[4][4];
        #pragma unroll
        for (int ks = 0; ks < 4; ++ks)
            #pragma unroll
            for (int nd = 0; nd < 4; ++nd)
                vf[ks][nd] = *(const bf16x8*)(Vp + ((size_t)(kt * 4 + ks) * 4 + nd) * 512 + lane * 8);
        if (kt > 0) {
            #pragma unroll
            for (int i = 0; i < 8; ++i) {
                int row = 2 * i + (lane >> 5);
                int col0 = (lane & 31) * 4;
                bf16x4 p4 = *(const bf16x4*)&Ps[prev][w][row][col0];
                f32x4 o;
                o[0] = (float)p4[0]; o[1] = (float)p4[1];
                o[2] = (float)p4[2]; o[3] = (float)p4[3];
                *(f32x4*)&Pp[(size_t)row * Sdim + (kt - 1) * KVB + col0] = o;
            }
        }
        #pragma unroll
        for (int ni = 0; ni < 8; ++ni) {
            f32x4 s = (f32x4){0.f, 0.f, 0.f, 0.f};
            s = __builtin_amdgcn_mfma_f32_16x16x32_bf16(qf[0], kf[ni][0], s, 0, 0, 0);
            s = __builtin_amdgcn_mfma_f32_16x16x32_bf16(qf[1], kf[ni][1], s, 0, 0, 0);
            #pragma unroll
            for (int j = 0; j < 4; ++j)
                Ps[cur][w][lg * 4 + j][ni * 16 + lr] = f2b(__expf(s[j]) * il[j]);
        }
        #pragma unroll
        for (int ks = 0; ks < 4; ++ks) {
            bf16x8 pa = *(const bf16x8*)&Ps[cur][w][lr][ks * 32 + lg * 8];
            #pragma unroll
            for (int nd = 0; nd < 4; ++nd)
                oacc[nd] = __builtin_amdgcn_mfma_f32_16x16x32_bf16(pa, vf[ks][nd], oacc[nd], 0, 0, 0);
        }
    }
    // epilogue: store last tile's band (band index 15&1 = 1)
    #pragma unroll
    for (int i = 0; i < 8; ++i) {
        int row = 2 * i + (lane >> 5);
        int col0 = (lane & 31) * 4;
        bf16x4 p4 = *(const bf16x4*)&Ps[1][w][row][col0];
        f32x4 o;
        o[0] = (float)p4[0]; o[1] = (float)p4[1];
        o[2] = (float)p4[2]; o[3] = (float)p4[3];
        *(f32x4*)&Pp[(size_t)row * Sdim + (Sdim - KVB) + col0] = o;
    }

    // epilogue: AO bf16 [B,S,E]
    #pragma unroll
    for (int nd = 0; nd < 4; ++nd)
        #pragma unroll
        for (int j = 0; j < 4; ++j) {
            int s = qt * 64 + w * 16 + lg * 4 + j;
            int d = nd * 16 + lr;
            AOb[((size_t)(b * Sdim + s)) * Edim + h * Ddim + d] = f2b(oacc[nd][j]);
        }
}

// ---- Kernel 3: output = AO @ Wo^T + bo -> d_out f32, m97-class GEMM.
__global__ __launch_bounds__(256) void k_oproj(
    const bf16_t* __restrict__ AOb, const bf16_t* __restrict__ Wob,
    const float* __restrict__ bo, float* __restrict__ out) {
    f32x4 acc[4][4];
    gemm_async(AOb + (size_t)blockIdx.y * 128 * Edim,
               Wob + (size_t)blockIdx.x * 128 * Edim, Edim, acc);
    const int tid = threadIdx.x, lane = tid & 63, w = tid >> 6;
    const int wm = w >> 1, wn = w & 1, lr = lane & 15, lg = lane >> 4;
    #pragma unroll
    for (int mi = 0; mi < 4; ++mi)
        #pragma unroll
        for (int ni = 0; ni < 4; ++ni)
            #pragma unroll
            for (int j = 0; j < 4; ++j) {
                int gm = blockIdx.y * 128 + wm * 64 + mi * 16 + lg * 4 + j;
                int gn = blockIdx.x * 128 + wn * 64 + ni * 16 + lr;
                out[(size_t)gm * Edim + gn] = acc[mi][ni][j] + bo[gn];
            }
}

extern "C" void kernel_launch(void* const* d_in, const int* in_sizes, int n_in,
                              void* d_out, int out_size, void* d_ws, size_t ws_size,
                              hipStream_t stream) {
    const float* query = (const float*)d_in[0];
    const float* key_  = (const float*)d_in[1];
    const float* value = (const float*)d_in[2];
    const float* Wq = (const float*)d_in[3];
    const float* bq = (const float*)d_in[4];
    const float* Wk = (const float*)d_in[5];
    const float* bk = (const float*)d_in[6];
    const float* Wv = (const float*)d_in[7];
    const float* bv = (const float*)d_in[8];
    const float* Wo = (const float*)d_in[9];
    const float* bo = (const float*)d_in[10];

    float* out = (float*)d_out;                      // [4096][1024]
    float* P = out + (size_t)MROWS * Edim;           // [32][2048][2048] attn weights
    const size_t PSZ = (size_t)32 * Sdim * Sdim;     // 134217728 floats

    const size_t WSZ = (size_t)Edim * Edim;                 // 1M elems per W
    const size_t HSD = (size_t)Bdim * Hdim * Sdim * Ddim;   // 4M elems
    bf16_t* Wb   = (bf16_t*)d_ws;       // 4 x [E,E]  (Wq*0.125, Wk, Wv, Wo)
    bf16_t* Qb   = Wb + 4 * WSZ;        // [B,H,S,D]  (pre-scaled)
    bf16_t* Kswz = Qb + HSD;            // fragment-major K
    bf16_t* Vswz = Kswz + HSD;          // fragment-major V
    bf16_t* AOb  = Vswz + HSD;          // [B,S,E]
    // Xb scratch lives in the TAIL of the P region (24MB of its last 48MB);
    // k_proj consumes it before k_attn overwrites all of P.
    bf16_t* Xb   = (bf16_t*)(P + PSZ - 6 * 1024 * 1024);

    k_convert<<<dim3(2048, 7), 256, 0, stream>>>(Wq, Wk, Wv, Wo, query, key_, value,
                                                 Wb, Xb);
    k_proj<<<dim3(8, 32, 3), 256, 0, stream>>>(Xb, Wb, bq, bk, bv, Qb, Kswz, Vswz);
    k_attn<<<dim3(1024), 256, 0, stream>>>(Qb, Kswz, Vswz, P, AOb);
    k_oproj<<<dim3(8, 32, 1), 256, 0, stream>>>(AOb, Wb + 3 * WSZ, bo, out);
}

// Round 16
// 280.670 us; speedup vs baseline: 1.9207x; 1.0758x over previous
//
#include <hip/hip_runtime.h>
#include <hip/hip_bf16.h>
#include <cstdint>
#include <cstddef>

#define Bdim 2
#define Sdim 2048
#define Edim 1024
#define Hdim 16
#define Ddim 64
#define KVB 128
#define MROWS (Bdim*Sdim)

typedef __bf16 bf16_t;
typedef __attribute__((ext_vector_type(8))) __bf16 bf16x8;
typedef __attribute__((ext_vector_type(4))) __bf16 bf16x4;
typedef __attribute__((ext_vector_type(4))) float f32x4;

typedef __attribute__((address_space(3))) uint8_t lds8_t;
typedef const __attribute__((address_space(1))) uint8_t glb8_t;

__device__ inline bf16_t f2b(float x) {
    unsigned u = __builtin_bit_cast(unsigned, x);
    unsigned r = u + 0x7fffu + ((u >> 16) & 1u);
    return __builtin_bit_cast(bf16_t, (unsigned short)(r >> 16));
}

// m97-class bf16 GEMM core: C[128x128] = A[128xK] * B^T (B row-major [128-col
// band][K]). 4 waves 2x2, 16x16x32 MFMA, 4x4 frags/wave. Staging via
// global_load_lds width=16 into LINEAR LDS [128][32] bf16.
__device__ inline void gemm_async(const bf16_t* A, const bf16_t* B, int K,
                                  f32x4 (&acc)[4][4]) {
    __shared__ __align__(16) bf16_t As[128 * 32];
    __shared__ __align__(16) bf16_t Bs[128 * 32];
    const int tid = threadIdx.x;
    const int lane = tid & 63;
    const int w = tid >> 6;
    const int wm = w >> 1, wn = w & 1;
    const int lr = lane & 15, lg = lane >> 4;

    #pragma unroll
    for (int mi = 0; mi < 4; ++mi)
        #pragma unroll
        for (int ni = 0; ni < 4; ++ni)
            acc[mi][ni] = (f32x4){0.f, 0.f, 0.f, 0.f};

    const int srow = (lane >> 2);
    const int scol = (lane & 3) * 8;

    for (int kt = 0; kt < K; kt += 32) {
        __syncthreads();
        #pragma unroll
        for (int i = 0; i < 2; ++i) {
            const int chunk = w * 2 + i;
            const int row = chunk * 16 + srow;
            __builtin_amdgcn_global_load_lds(
                (glb8_t*)(A + (size_t)row * K + kt + scol),
                (lds8_t*)(As + chunk * 512), 16, 0, 0);
            __builtin_amdgcn_global_load_lds(
                (glb8_t*)(B + (size_t)row * K + kt + scol),
                (lds8_t*)(Bs + chunk * 512), 16, 0, 0);
        }
        __syncthreads();
        bf16x8 af[4], bf[4];
        #pragma unroll
        for (int mi = 0; mi < 4; ++mi)
            af[mi] = *(const bf16x8*)&As[(wm * 64 + mi * 16 + lr) * 32 + lg * 8];
        #pragma unroll
        for (int ni = 0; ni < 4; ++ni)
            bf[ni] = *(const bf16x8*)&Bs[(wn * 64 + ni * 16 + lr) * 32 + lg * 8];
        #pragma unroll
        for (int mi = 0; mi < 4; ++mi)
            #pragma unroll
            for (int ni = 0; ni < 4; ++ni)
                acc[mi][ni] = __builtin_amdgcn_mfma_f32_16x16x32_bf16(
                    af[mi], bf[ni], acc[mi][ni], 0, 0, 0);
    }
}

// ---- Kernel 0: convert weights AND the 3 input activations to bf16.
__global__ __launch_bounds__(256) void k_convert(
    const float* __restrict__ Wq, const float* __restrict__ Wk,
    const float* __restrict__ Wv, const float* __restrict__ Wo,
    const float* __restrict__ xq, const float* __restrict__ xk,
    const float* __restrict__ xv,
    bf16_t* __restrict__ Wb, bf16_t* __restrict__ Xb) {
    const int z = blockIdx.y;
    const float* src;
    bf16_t* d;
    float scale = 1.0f;
    if (z < 4) {
        if (blockIdx.x >= 512) return;
        src = (z == 0) ? Wq : (z == 1) ? Wk : (z == 2) ? Wv : Wo;
        scale = (z == 0) ? 0.125f : 1.0f;
        d = Wb + (size_t)z * Edim * Edim;
    } else {
        src = (z == 4) ? xq : (z == 5) ? xk : xv;
        d = Xb + (size_t)(z - 4) * MROWS * Edim;
    }
    const size_t i = (size_t)blockIdx.x * 256 + threadIdx.x;
    const float4* s4 = (const float4*)(src + i * 8);
    float4 a = s4[0], b = s4[1];
    bf16x8 v;
    v[0] = f2b(a.x * scale); v[1] = f2b(a.y * scale);
    v[2] = f2b(a.z * scale); v[3] = f2b(a.w * scale);
    v[4] = f2b(b.x * scale); v[5] = f2b(b.y * scale);
    v[6] = f2b(b.z * scale); v[7] = f2b(b.w * scale);
    *(bf16x8*)(d + i * 8) = v;
}

// ---- Kernel 1: QKV projections, m97-class bf16 GEMM.
// Q (pre-scaled by 0.125) -> [B,H,S,D]; K,V -> MFMA-fragment-major swizzled:
//   Kswz[bh][s/16][d/8][s%16][d%8]
//   Vswz[bh][s/32][d/16][(s/8)%4][d%16][s%8]
__global__ __launch_bounds__(256) void k_proj(
    const bf16_t* __restrict__ Xb, const bf16_t* __restrict__ Wb,
    const float* __restrict__ bq, const float* __restrict__ bk, const float* __restrict__ bv,
    bf16_t* __restrict__ Qb, bf16_t* __restrict__ Kswz, bf16_t* __restrict__ Vswz) {
    const int z = blockIdx.z;
    const bf16_t* X = Xb + (size_t)z * MROWS * Edim;
    const bf16_t* W = Wb + (size_t)z * Edim * Edim;
    const float* bias = (z == 0) ? bq : (z == 1) ? bk : bv;
    const float bscale = (z == 0) ? 0.125f : 1.0f;
    const int tm = blockIdx.y, tn = blockIdx.x;
    f32x4 acc[4][4];
    gemm_async(X + (size_t)tm * 128 * Edim, W + (size_t)tn * 128 * Edim, Edim, acc);
    const int tid = threadIdx.x, lane = tid & 63, w = tid >> 6;
    const int wm = w >> 1, wn = w & 1, lr = lane & 15, lg = lane >> 4;
    #pragma unroll
    for (int mi = 0; mi < 4; ++mi)
        #pragma unroll
        for (int ni = 0; ni < 4; ++ni)
            #pragma unroll
            for (int j = 0; j < 4; ++j) {
                int gm = tm * 128 + wm * 64 + mi * 16 + lg * 4 + j;
                int gn = tn * 128 + wn * 64 + ni * 16 + lr;
                float v = acc[mi][ni][j] + bias[gn] * bscale;
                int b = gm >> 11, s = gm & (Sdim - 1);
                int h = gn >> 6, d = gn & (Ddim - 1);
                size_t bh = (size_t)(b * Hdim + h);
                if (z == 0) {
                    Qb[(bh * Sdim + s) * Ddim + d] = f2b(v);
                } else if (z == 1) {
                    size_t idx = ((bh * (Sdim / 16) + (s >> 4)) * 8 + (d >> 3)) * 128
                               + (s & 15) * 8 + (d & 7);
                    Kswz[idx] = f2b(v);
                } else {
                    size_t idx = (((bh * (Sdim / 32) + (s >> 5)) * 4 + (d >> 4)) * 4
                               + ((s >> 3) & 3)) * 128 + (d & 15) * 8 + (s & 7);
                    Vswz[idx] = f2b(v);
                }
            }
}

// ---- Kernel 2: fused attention v11 = r9 champion + phase-1 software
// pipeline (3-buffer rotation, 64 groups of 2 fragments, depth-2 prefetch)
// + s_setprio around MFMA clusters. Phase 2 unchanged.
__global__ __launch_bounds__(256) void k_attn(
    const bf16_t* __restrict__ Qb, const bf16_t* __restrict__ Kswz,
    const bf16_t* __restrict__ Vswz, float* __restrict__ P, bf16_t* __restrict__ AOb) {
    const int wg = blockIdx.x;
    const int id = ((wg & 7) << 7) | (wg >> 3);   // bijective XCD swizzle
    const int bh = id >> 5, qt = id & 31;
    const int b = bh >> 4, h = bh & 15;
    const int tid = threadIdx.x, lane = tid & 63, w = tid >> 6;
    const int lr = lane & 15, lg = lane >> 4;

    __shared__ bf16_t Ps[2][4][16][132];   // double-buffered per-wave P bands

    const bf16_t* Qp = Qb + ((size_t)bh * Sdim + qt * 64 + w * 16) * Ddim;
    const bf16_t* Kp = Kswz + (size_t)bh * Sdim * Ddim;   // fragment-major
    const bf16_t* Vp = Vswz + (size_t)bh * Ddim * Sdim;   // fragment-major
    float* Pp = P + (size_t)bh * Sdim * Sdim + (size_t)(qt * 64 + w * 16) * Sdim;

    bf16x8 qf[2];
    #pragma unroll
    for (int kk = 0; kk < 2; ++kk)
        qf[kk] = *(const bf16x8*)(Qp + lr * Ddim + kk * 32 + lg * 8);

    // ---------------- Phase 1: row sums of exp(s), software-pipelined ------
    // 128 fragments, fragment f at Kp + f*1024; 64 groups of 2 fragments,
    // 3 rotating buffers -> 2 groups (8 loads) always in flight.
    float lsum[4] = {0.f, 0.f, 0.f, 0.f};
    {
        bf16x8 bA[2][2], bB[2][2], bC[2][2];
#define LOADG(buf, g) { \
            _Pragma("unroll") \
            for (int t = 0; t < 2; ++t) { \
                const bf16_t* kp = Kp + (size_t)((g) * 2 + t) * 1024 + lane * 8; \
                buf[t][0] = *(const bf16x8*)(kp); \
                buf[t][1] = *(const bf16x8*)(kp + 512); \
            } }
#define COMPG(buf) { \
            __builtin_amdgcn_s_setprio(1); \
            f32x4 s0 = (f32x4){0.f,0.f,0.f,0.f}, s1 = (f32x4){0.f,0.f,0.f,0.f}; \
            s0 = __builtin_amdgcn_mfma_f32_16x16x32_bf16(qf[0], buf[0][0], s0, 0, 0, 0); \
            s1 = __builtin_amdgcn_mfma_f32_16x16x32_bf16(qf[0], buf[1][0], s1, 0, 0, 0); \
            s0 = __builtin_amdgcn_mfma_f32_16x16x32_bf16(qf[1], buf[0][1], s0, 0, 0, 0); \
            s1 = __builtin_amdgcn_mfma_f32_16x16x32_bf16(qf[1], buf[1][1], s1, 0, 0, 0); \
            __builtin_amdgcn_s_setprio(0); \
            _Pragma("unroll") \
            for (int j = 0; j < 4; ++j) lsum[j] += __expf(s0[j]) + __expf(s1[j]); }
        LOADG(bA, 0); LOADG(bB, 1);
        for (int g = 0; g < 60; g += 3) {
            LOADG(bC, g + 2); COMPG(bA);
            LOADG(bA, g + 3); COMPG(bB);
            LOADG(bB, g + 4); COMPG(bC);
        }
        // after loop: bA holds 60, bB holds 61
        LOADG(bC, 62); COMPG(bA);
        LOADG(bA, 63); COMPG(bB);
        COMPG(bC); COMPG(bA);
#undef LOADG
#undef COMPG
    }
    #pragma unroll
    for (int mask = 1; mask <= 8; mask <<= 1)
        #pragma unroll
        for (int j = 0; j < 4; ++j)
            lsum[j] += __shfl_xor(lsum[j], mask);
    float il[4];
    #pragma unroll
    for (int j = 0; j < 4; ++j) il[j] = 1.0f / lsum[j];

    // ---------------- Phase 2: pipelined P store + O = P.V ----------------
    f32x4 oacc[4];
    #pragma unroll
    for (int nd = 0; nd < 4; ++nd) oacc[nd] = (f32x4){0.f, 0.f, 0.f, 0.f};

    for (int kt = 0; kt < Sdim / KVB; ++kt) {
        const int cur = kt & 1, prev = cur ^ 1;
        bf16x8 kf[8][2];
        #pragma unroll
        for (int ni = 0; ni < 8; ++ni) {
            const bf16_t* kp = Kp + (size_t)(kt * 8 + ni) * 1024 + lane * 8;
            kf[ni][0] = *(const bf16x8*)(kp);
            kf[ni][1] = *(const bf16x8*)(kp + 512);
        }
        bf16x8 vf[4][4];
        #pragma unroll
        for (int ks = 0; ks < 4; ++ks)
            #pragma unroll
            for (int nd = 0; nd < 4; ++nd)
                vf[ks][nd] = *(const bf16x8*)(Vp + ((size_t)(kt * 4 + ks) * 4 + nd) * 512 + lane * 8);
        if (kt > 0) {
            #pragma unroll
            for (int i = 0; i < 8; ++i) {
                int row = 2 * i + (lane >> 5);
                int col0 = (lane & 31) * 4;
                bf16x4 p4 = *(const bf16x4*)&Ps[prev][w][row][col0];
                f32x4 o;
                o[0] = (float)p4[0]; o[1] = (float)p4[1];
                o[2] = (float)p4[2]; o[3] = (float)p4[3];
                *(f32x4*)&Pp[(size_t)row * Sdim + (kt - 1) * KVB + col0] = o;
            }
        }
        __builtin_amdgcn_s_setprio(1);
        #pragma unroll
        for (int ni = 0; ni < 8; ++ni) {
            f32x4 s = (f32x4){0.f, 0.f, 0.f, 0.f};
            s = __builtin_amdgcn_mfma_f32_16x16x32_bf16(qf[0], kf[ni][0], s, 0, 0, 0);
            s = __builtin_amdgcn_mfma_f32_16x16x32_bf16(qf[1], kf[ni][1], s, 0, 0, 0);
            #pragma unroll
            for (int j = 0; j < 4; ++j)
                Ps[cur][w][lg * 4 + j][ni * 16 + lr] = f2b(__expf(s[j]) * il[j]);
        }
        __builtin_amdgcn_s_setprio(0);
        __builtin_amdgcn_s_setprio(1);
        #pragma unroll
        for (int ks = 0; ks < 4; ++ks) {
            bf16x8 pa = *(const bf16x8*)&Ps[cur][w][lr][ks * 32 + lg * 8];
            #pragma unroll
            for (int nd = 0; nd < 4; ++nd)
                oacc[nd] = __builtin_amdgcn_mfma_f32_16x16x32_bf16(pa, vf[ks][nd], oacc[nd], 0, 0, 0);
        }
        __builtin_amdgcn_s_setprio(0);
    }
    // epilogue: store last tile's band (band index 15&1 = 1)
    #pragma unroll
    for (int i = 0; i < 8; ++i) {
        int row = 2 * i + (lane >> 5);
        int col0 = (lane & 31) * 4;
        bf16x4 p4 = *(const bf16x4*)&Ps[1][w][row][col0];
        f32x4 o;
        o[0] = (float)p4[0]; o[1] = (float)p4[1];
        o[2] = (float)p4[2]; o[3] = (float)p4[3];
        *(f32x4*)&Pp[(size_t)row * Sdim + (Sdim - KVB) + col0] = o;
    }

    // epilogue: AO bf16 [B,S,E]
    #pragma unroll
    for (int nd = 0; nd < 4; ++nd)
        #pragma unroll
        for (int j = 0; j < 4; ++j) {
            int s = qt * 64 + w * 16 + lg * 4 + j;
            int d = nd * 16 + lr;
            AOb[((size_t)(b * Sdim + s)) * Edim + h * Ddim + d] = f2b(oacc[nd][j]);
        }
}

// ---- Kernel 3: output = AO @ Wo^T + bo -> d_out f32, m97-class GEMM.
__global__ __launch_bounds__(256) void k_oproj(
    const bf16_t* __restrict__ AOb, const bf16_t* __restrict__ Wob,
    const float* __restrict__ bo, float* __restrict__ out) {
    f32x4 acc[4][4];
    gemm_async(AOb + (size_t)blockIdx.y * 128 * Edim,
               Wob + (size_t)blockIdx.x * 128 * Edim, Edim, acc);
    const int tid = threadIdx.x, lane = tid & 63, w = tid >> 6;
    const int wm = w >> 1, wn = w & 1, lr = lane & 15, lg = lane >> 4;
    #pragma unroll
    for (int mi = 0; mi < 4; ++mi)
        #pragma unroll
        for (int ni = 0; ni < 4; ++ni)
            #pragma unroll
            for (int j = 0; j < 4; ++j) {
                int gm = blockIdx.y * 128 + wm * 64 + mi * 16 + lg * 4 + j;
                int gn = blockIdx.x * 128 + wn * 64 + ni * 16 + lr;
                out[(size_t)gm * Edim + gn] = acc[mi][ni][j] + bo[gn];
            }
}

extern "C" void kernel_launch(void* const* d_in, const int* in_sizes, int n_in,
                              void* d_out, int out_size, void* d_ws, size_t ws_size,
                              hipStream_t stream) {
    const float* query = (const float*)d_in[0];
    const float* key_  = (const float*)d_in[1];
    const float* value = (const float*)d_in[2];
    const float* Wq = (const float*)d_in[3];
    const float* bq = (const float*)d_in[4];
    const float* Wk = (const float*)d_in[5];
    const float* bk = (const float*)d_in[6];
    const float* Wv = (const float*)d_in[7];
    const float* bv = (const float*)d_in[8];
    const float* Wo = (const float*)d_in[9];
    const float* bo = (const float*)d_in[10];

    float* out = (float*)d_out;                      // [4096][1024]
    float* P = out + (size_t)MROWS * Edim;           // [32][2048][2048] attn weights
    const size_t PSZ = (size_t)32 * Sdim * Sdim;     // 134217728 floats

    const size_t WSZ = (size_t)Edim * Edim;                 // 1M elems per W
    const size_t HSD = (size_t)Bdim * Hdim * Sdim * Ddim;   // 4M elems
    bf16_t* Wb   = (bf16_t*)d_ws;       // 4 x [E,E]  (Wq*0.125, Wk, Wv, Wo)
    bf16_t* Qb   = Wb + 4 * WSZ;        // [B,H,S,D]  (pre-scaled)
    bf16_t* Kswz = Qb + HSD;            // fragment-major K
    bf16_t* Vswz = Kswz + HSD;          // fragment-major V
    bf16_t* AOb  = Vswz + HSD;          // [B,S,E]
    // Xb scratch lives in the TAIL of the P region (24MB of its last 48MB);
    // k_proj consumes it before k_attn overwrites all of P.
    bf16_t* Xb   = (bf16_t*)(P + PSZ - 6 * 1024 * 1024);

    k_convert<<<dim3(2048, 7), 256, 0, stream>>>(Wq, Wk, Wv, Wo, query, key_, value,
                                                 Wb, Xb);
    k_proj<<<dim3(8, 32, 3), 256, 0, stream>>>(Xb, Wb, bq, bk, bv, Qb, Kswz, Vswz);
    k_attn<<<dim3(1024), 256, 0, stream>>>(Qb, Kswz, Vswz, P, AOb);
    k_oproj<<<dim3(8, 32, 1), 256, 0, stream>>>(AOb, Wb + 3 * WSZ, bo, out);
}

// Round 17
// 272.275 us; speedup vs baseline: 1.9799x; 1.0308x over previous
//
#include <hip/hip_runtime.h>
#include <hip/hip_bf16.h>
#include <cstdint>
#include <cstddef>

#define Bdim 2
#define Sdim 2048
#define Edim 1024
#define Hdim 16
#define Ddim 64
#define KVB 128
#define MROWS (Bdim*Sdim)

typedef __bf16 bf16_t;
typedef __attribute__((ext_vector_type(8))) __bf16 bf16x8;
typedef __attribute__((ext_vector_type(4))) __bf16 bf16x4;
typedef __attribute__((ext_vector_type(4))) float f32x4;

typedef __attribute__((address_space(3))) uint8_t lds8_t;
typedef const __attribute__((address_space(1))) uint8_t glb8_t;

__device__ inline bf16_t f2b(float x) {
    unsigned u = __builtin_bit_cast(unsigned, x);
    unsigned r = u + 0x7fffu + ((u >> 16) & 1u);
    return __builtin_bit_cast(bf16_t, (unsigned short)(r >> 16));
}

// m97-class bf16 GEMM core: C[128x128] = A[128xK] * B^T (B row-major [128-col
// band][K]). 4 waves 2x2, 16x16x32 MFMA, 4x4 frags/wave. Staging via
// global_load_lds width=16 into LINEAR LDS [128][32] bf16.
__device__ inline void gemm_async(const bf16_t* A, const bf16_t* B, int K,
                                  f32x4 (&acc)[4][4]) {
    __shared__ __align__(16) bf16_t As[128 * 32];
    __shared__ __align__(16) bf16_t Bs[128 * 32];
    const int tid = threadIdx.x;
    const int lane = tid & 63;
    const int w = tid >> 6;
    const int wm = w >> 1, wn = w & 1;
    const int lr = lane & 15, lg = lane >> 4;

    #pragma unroll
    for (int mi = 0; mi < 4; ++mi)
        #pragma unroll
        for (int ni = 0; ni < 4; ++ni)
            acc[mi][ni] = (f32x4){0.f, 0.f, 0.f, 0.f};

    const int srow = (lane >> 2);
    const int scol = (lane & 3) * 8;

    for (int kt = 0; kt < K; kt += 32) {
        __syncthreads();
        #pragma unroll
        for (int i = 0; i < 2; ++i) {
            const int chunk = w * 2 + i;
            const int row = chunk * 16 + srow;
            __builtin_amdgcn_global_load_lds(
                (glb8_t*)(A + (size_t)row * K + kt + scol),
                (lds8_t*)(As + chunk * 512), 16, 0, 0);
            __builtin_amdgcn_global_load_lds(
                (glb8_t*)(B + (size_t)row * K + kt + scol),
                (lds8_t*)(Bs + chunk * 512), 16, 0, 0);
        }
        __syncthreads();
        bf16x8 af[4], bf[4];
        #pragma unroll
        for (int mi = 0; mi < 4; ++mi)
            af[mi] = *(const bf16x8*)&As[(wm * 64 + mi * 16 + lr) * 32 + lg * 8];
        #pragma unroll
        for (int ni = 0; ni < 4; ++ni)
            bf[ni] = *(const bf16x8*)&Bs[(wn * 64 + ni * 16 + lr) * 32 + lg * 8];
        #pragma unroll
        for (int mi = 0; mi < 4; ++mi)
            #pragma unroll
            for (int ni = 0; ni < 4; ++ni)
                acc[mi][ni] = __builtin_amdgcn_mfma_f32_16x16x32_bf16(
                    af[mi], bf[ni], acc[mi][ni], 0, 0, 0);
    }
}

// ---- Kernel 0: convert weights AND the 3 input activations to bf16.
__global__ __launch_bounds__(256) void k_convert(
    const float* __restrict__ Wq, const float* __restrict__ Wk,
    const float* __restrict__ Wv, const float* __restrict__ Wo,
    const float* __restrict__ xq, const float* __restrict__ xk,
    const float* __restrict__ xv,
    bf16_t* __restrict__ Wb, bf16_t* __restrict__ Xb) {
    const int z = blockIdx.y;
    const float* src;
    bf16_t* d;
    float scale = 1.0f;
    if (z < 4) {
        if (blockIdx.x >= 512) return;
        src = (z == 0) ? Wq : (z == 1) ? Wk : (z == 2) ? Wv : Wo;
        scale = (z == 0) ? 0.125f : 1.0f;
        d = Wb + (size_t)z * Edim * Edim;
    } else {
        src = (z == 4) ? xq : (z == 5) ? xk : xv;
        d = Xb + (size_t)(z - 4) * MROWS * Edim;
    }
    const size_t i = (size_t)blockIdx.x * 256 + threadIdx.x;
    const float4* s4 = (const float4*)(src + i * 8);
    float4 a = s4[0], b = s4[1];
    bf16x8 v;
    v[0] = f2b(a.x * scale); v[1] = f2b(a.y * scale);
    v[2] = f2b(a.z * scale); v[3] = f2b(a.w * scale);
    v[4] = f2b(b.x * scale); v[5] = f2b(b.y * scale);
    v[6] = f2b(b.z * scale); v[7] = f2b(b.w * scale);
    *(bf16x8*)(d + i * 8) = v;
}

// ---- Kernel 1: QKV projections, m97-class bf16 GEMM.
// Q (pre-scaled by 0.125) -> [B,H,S,D]; K,V -> MFMA-fragment-major swizzled:
//   Kswz[bh][s/16][d/8][s%16][d%8]
//   Vswz[bh][s/32][d/16][(s/8)%4][d%16][s%8]
__global__ __launch_bounds__(256) void k_proj(
    const bf16_t* __restrict__ Xb, const bf16_t* __restrict__ Wb,
    const float* __restrict__ bq, const float* __restrict__ bk, const float* __restrict__ bv,
    bf16_t* __restrict__ Qb, bf16_t* __restrict__ Kswz, bf16_t* __restrict__ Vswz) {
    const int z = blockIdx.z;
    const bf16_t* X = Xb + (size_t)z * MROWS * Edim;
    const bf16_t* W = Wb + (size_t)z * Edim * Edim;
    const float* bias = (z == 0) ? bq : (z == 1) ? bk : bv;
    const float bscale = (z == 0) ? 0.125f : 1.0f;
    const int tm = blockIdx.y, tn = blockIdx.x;
    f32x4 acc[4][4];
    gemm_async(X + (size_t)tm * 128 * Edim, W + (size_t)tn * 128 * Edim, Edim, acc);
    const int tid = threadIdx.x, lane = tid & 63, w = tid >> 6;
    const int wm = w >> 1, wn = w & 1, lr = lane & 15, lg = lane >> 4;
    #pragma unroll
    for (int mi = 0; mi < 4; ++mi)
        #pragma unroll
        for (int ni = 0; ni < 4; ++ni)
            #pragma unroll
            for (int j = 0; j < 4; ++j) {
                int gm = tm * 128 + wm * 64 + mi * 16 + lg * 4 + j;
                int gn = tn * 128 + wn * 64 + ni * 16 + lr;
                float v = acc[mi][ni][j] + bias[gn] * bscale;
                int b = gm >> 11, s = gm & (Sdim - 1);
                int h = gn >> 6, d = gn & (Ddim - 1);
                size_t bh = (size_t)(b * Hdim + h);
                if (z == 0) {
                    Qb[(bh * Sdim + s) * Ddim + d] = f2b(v);
                } else if (z == 1) {
                    size_t idx = ((bh * (Sdim / 16) + (s >> 4)) * 8 + (d >> 3)) * 128
                               + (s & 15) * 8 + (d & 7);
                    Kswz[idx] = f2b(v);
                } else {
                    size_t idx = (((bh * (Sdim / 32) + (s >> 5)) * 4 + (d >> 4)) * 4
                               + ((s >> 3) & 3)) * 128 + (d & 15) * 8 + (s & 7);
                    Vswz[idx] = f2b(v);
                }
            }
}

// ---- Kernel 2: fused attention v12 = v11 with COLUMN-SPLIT phase 1.
// Phase 1: wave w computes scores for ALL 64 block rows over cols
// [w*512,(w+1)*512) -> per-wave K traffic /4, 8 MFMA per fragment-pair load
// (was 2). 3-buffer rotation + setprio retained. One LDS sum-reduction +
// one barrier at phase end. Phase 2 unchanged (row-split, r16 structure).
__global__ __launch_bounds__(256) void k_attn(
    const bf16_t* __restrict__ Qb, const bf16_t* __restrict__ Kswz,
    const bf16_t* __restrict__ Vswz, float* __restrict__ P, bf16_t* __restrict__ AOb) {
    const int wg = blockIdx.x;
    const int id = ((wg & 7) << 7) | (wg >> 3);   // bijective XCD swizzle
    const int bh = id >> 5, qt = id & 31;
    const int b = bh >> 4, h = bh & 15;
    const int tid = threadIdx.x, lane = tid & 63, w = tid >> 6;
    const int lr = lane & 15, lg = lane >> 4;

    __shared__ bf16_t Ps[2][4][16][132];   // double-buffered per-wave P bands
    __shared__ float sum_lds[4][64];       // phase-1 partial row sums

    const bf16_t* Qp0 = Qb + ((size_t)bh * Sdim + qt * 64) * Ddim;       // block base
    const bf16_t* Qp  = Qp0 + (size_t)(w * 16) * Ddim;                   // wave's rows
    const bf16_t* Kp = Kswz + (size_t)bh * Sdim * Ddim;   // fragment-major
    const bf16_t* Vp = Vswz + (size_t)bh * Ddim * Sdim;   // fragment-major
    float* Pp = P + (size_t)bh * Sdim * Sdim + (size_t)(qt * 64 + w * 16) * Sdim;

    // ---------------- Phase 1: column-split row sums of exp(s) -------------
    // qf1[rg]: Q fragments for block rows rg*16+lr (all 64 rows).
    {
        bf16x8 qf1[4][2];
        #pragma unroll
        for (int rg = 0; rg < 4; ++rg)
            #pragma unroll
            for (int kk = 0; kk < 2; ++kk)
                qf1[rg][kk] = *(const bf16x8*)(Qp0 + (rg * 16 + lr) * Ddim + kk * 32 + lg * 8);

        float lsum[4][4];
        #pragma unroll
        for (int rg = 0; rg < 4; ++rg)
            #pragma unroll
            for (int j = 0; j < 4; ++j) lsum[rg][j] = 0.f;

        const bf16_t* Kw = Kp + (size_t)w * 32 * 1024;   // wave's 32 fragments
        bf16x8 bA[2][2], bB[2][2], bC[2][2];
#define LOADG(buf, g) { \
            _Pragma("unroll") \
            for (int t = 0; t < 2; ++t) { \
                const bf16_t* kp = Kw + (size_t)((g) * 2 + t) * 1024 + lane * 8; \
                buf[t][0] = *(const bf16x8*)(kp); \
                buf[t][1] = *(const bf16x8*)(kp + 512); \
            } }
#define COMPG(buf) { \
            f32x4 sv[2][4]; \
            __builtin_amdgcn_s_setprio(1); \
            _Pragma("unroll") \
            for (int t = 0; t < 2; ++t) \
                _Pragma("unroll") \
                for (int rg = 0; rg < 4; ++rg) { \
                    f32x4 s = (f32x4){0.f, 0.f, 0.f, 0.f}; \
                    s = __builtin_amdgcn_mfma_f32_16x16x32_bf16(qf1[rg][0], buf[t][0], s, 0, 0, 0); \
                    s = __builtin_amdgcn_mfma_f32_16x16x32_bf16(qf1[rg][1], buf[t][1], s, 0, 0, 0); \
                    sv[t][rg] = s; \
                } \
            __builtin_amdgcn_s_setprio(0); \
            _Pragma("unroll") \
            for (int t = 0; t < 2; ++t) \
                _Pragma("unroll") \
                for (int rg = 0; rg < 4; ++rg) \
                    _Pragma("unroll") \
                    for (int j = 0; j < 4; ++j) \
                        lsum[rg][j] += __expf(sv[t][rg][j]); }
        LOADG(bA, 0); LOADG(bB, 1);
        for (int g = 0; g < 12; g += 3) {
            LOADG(bC, g + 2); COMPG(bA);
            LOADG(bA, g + 3); COMPG(bB);
            LOADG(bB, g + 4); COMPG(bC);
        }
        LOADG(bC, 14); COMPG(bA);
        LOADG(bA, 15); COMPG(bB);
        COMPG(bC); COMPG(bA);
#undef LOADG
#undef COMPG
        #pragma unroll
        for (int mask = 1; mask <= 8; mask <<= 1)
            #pragma unroll
            for (int rg = 0; rg < 4; ++rg)
                #pragma unroll
                for (int j = 0; j < 4; ++j)
                    lsum[rg][j] += __shfl_xor(lsum[rg][j], mask);
        if (lr == 0)
            #pragma unroll
            for (int rg = 0; rg < 4; ++rg)
                #pragma unroll
                for (int j = 0; j < 4; ++j)
                    sum_lds[w][rg * 16 + lg * 4 + j] = lsum[rg][j];
    }
    __syncthreads();
    float il[4];
    #pragma unroll
    for (int j = 0; j < 4; ++j) {
        int row = w * 16 + lg * 4 + j;
        il[j] = 1.0f / (sum_lds[0][row] + sum_lds[1][row] +
                        sum_lds[2][row] + sum_lds[3][row]);
    }

    // Q fragments for phase 2 (wave's own 16 rows).
    bf16x8 qf[2];
    #pragma unroll
    for (int kk = 0; kk < 2; ++kk)
        qf[kk] = *(const bf16x8*)(Qp + lr * Ddim + kk * 32 + lg * 8);

    // ---------------- Phase 2: pipelined P store + O = P.V ----------------
    f32x4 oacc[4];
    #pragma unroll
    for (int nd = 0; nd < 4; ++nd) oacc[nd] = (f32x4){0.f, 0.f, 0.f, 0.f};

    for (int kt = 0; kt < Sdim / KVB; ++kt) {
        const int cur = kt & 1, prev = cur ^ 1;
        bf16x8 kf[8][2];
        #pragma unroll
        for (int ni = 0; ni < 8; ++ni) {
            const bf16_t* kp = Kp + (size_t)(kt * 8 + ni) * 1024 + lane * 8;
            kf[ni][0] = *(const bf16x8*)(kp);
            kf[ni][1] = *(const bf16x8*)(kp + 512);
        }
        bf16x8 vf[4][4];
        #pragma unroll
        for (int ks = 0; ks < 4; ++ks)
            #pragma unroll
            for (int nd = 0; nd < 4; ++nd)
                vf[ks][nd] = *(const bf16x8*)(Vp + ((size_t)(kt * 4 + ks) * 4 + nd) * 512 + lane * 8);
        if (kt > 0) {
            #pragma unroll
            for (int i = 0; i < 8; ++i) {
                int row = 2 * i + (lane >> 5);
                int col0 = (lane & 31) * 4;
                bf16x4 p4 = *(const bf16x4*)&Ps[prev][w][row][col0];
                f32x4 o;
                o[0] = (float)p4[0]; o[1] = (float)p4[1];
                o[2] = (float)p4[2]; o[3] = (float)p4[3];
                *(f32x4*)&Pp[(size_t)row * Sdim + (kt - 1) * KVB + col0] = o;
            }
        }
        __builtin_amdgcn_s_setprio(1);
        #pragma unroll
        for (int ni = 0; ni < 8; ++ni) {
            f32x4 s = (f32x4){0.f, 0.f, 0.f, 0.f};
            s = __builtin_amdgcn_mfma_f32_16x16x32_bf16(qf[0], kf[ni][0], s, 0, 0, 0);
            s = __builtin_amdgcn_mfma_f32_16x16x32_bf16(qf[1], kf[ni][1], s, 0, 0, 0);
            #pragma unroll
            for (int j = 0; j < 4; ++j)
                Ps[cur][w][lg * 4 + j][ni * 16 + lr] = f2b(__expf(s[j]) * il[j]);
        }
        __builtin_amdgcn_s_setprio(0);
        __builtin_amdgcn_s_setprio(1);
        #pragma unroll
        for (int ks = 0; ks < 4; ++ks) {
            bf16x8 pa = *(const bf16x8*)&Ps[cur][w][lr][ks * 32 + lg * 8];
            #pragma unroll
            for (int nd = 0; nd < 4; ++nd)
                oacc[nd] = __builtin_amdgcn_mfma_f32_16x16x32_bf16(pa, vf[ks][nd], oacc[nd], 0, 0, 0);
        }
        __builtin_amdgcn_s_setprio(0);
    }
    // epilogue: store last tile's band (band index 15&1 = 1)
    #pragma unroll
    for (int i = 0; i < 8; ++i) {
        int row = 2 * i + (lane >> 5);
        int col0 = (lane & 31) * 4;
        bf16x4 p4 = *(const bf16x4*)&Ps[1][w][row][col0];
        f32x4 o;
        o[0] = (float)p4[0]; o[1] = (float)p4[1];
        o[2] = (float)p4[2]; o[3] = (float)p4[3];
        *(f32x4*)&Pp[(size_t)row * Sdim + (Sdim - KVB) + col0] = o;
    }

    // epilogue: AO bf16 [B,S,E]
    #pragma unroll
    for (int nd = 0; nd < 4; ++nd)
        #pragma unroll
        for (int j = 0; j < 4; ++j) {
            int s = qt * 64 + w * 16 + lg * 4 + j;
            int d = nd * 16 + lr;
            AOb[((size_t)(b * Sdim + s)) * Edim + h * Ddim + d] = f2b(oacc[nd][j]);
        }
}

// ---- Kernel 3: output = AO @ Wo^T + bo -> d_out f32, m97-class GEMM.
__global__ __launch_bounds__(256) void k_oproj(
    const bf16_t* __restrict__ AOb, const bf16_t* __restrict__ Wob,
    const float* __restrict__ bo, float* __restrict__ out) {
    f32x4 acc[4][4];
    gemm_async(AOb + (size_t)blockIdx.y * 128 * Edim,
               Wob + (size_t)blockIdx.x * 128 * Edim, Edim, acc);
    const int tid = threadIdx.x, lane = tid & 63, w = tid >> 6;
    const int wm = w >> 1, wn = w & 1, lr = lane & 15, lg = lane >> 4;
    #pragma unroll
    for (int mi = 0; mi < 4; ++mi)
        #pragma unroll
        for (int ni = 0; ni < 4; ++ni)
            #pragma unroll
            for (int j = 0; j < 4; ++j) {
                int gm = blockIdx.y * 128 + wm * 64 + mi * 16 + lg * 4 + j;
                int gn = blockIdx.x * 128 + wn * 64 + ni * 16 + lr;
                out[(size_t)gm * Edim + gn] = acc[mi][ni][j] + bo[gn];
            }
}

extern "C" void kernel_launch(void* const* d_in, const int* in_sizes, int n_in,
                              void* d_out, int out_size, void* d_ws, size_t ws_size,
                              hipStream_t stream) {
    const float* query = (const float*)d_in[0];
    const float* key_  = (const float*)d_in[1];
    const float* value = (const float*)d_in[2];
    const float* Wq = (const float*)d_in[3];
    const float* bq = (const float*)d_in[4];
    const float* Wk = (const float*)d_in[5];
    const float* bk = (const float*)d_in[6];
    const float* Wv = (const float*)d_in[7];
    const float* bv = (const float*)d_in[8];
    const float* Wo = (const float*)d_in[9];
    const float* bo = (const float*)d_in[10];

    float* out = (float*)d_out;                      // [4096][1024]
    float* P = out + (size_t)MROWS * Edim;           // [32][2048][2048] attn weights
    const size_t PSZ = (size_t)32 * Sdim * Sdim;     // 134217728 floats

    const size_t WSZ = (size_t)Edim * Edim;                 // 1M elems per W
    const size_t HSD = (size_t)Bdim * Hdim * Sdim * Ddim;   // 4M elems
    bf16_t* Wb   = (bf16_t*)d_ws;       // 4 x [E,E]  (Wq*0.125, Wk, Wv, Wo)
    bf16_t* Qb   = Wb + 4 * WSZ;        // [B,H,S,D]  (pre-scaled)
    bf16_t* Kswz = Qb + HSD;            // fragment-major K
    bf16_t* Vswz = Kswz + HSD;          // fragment-major V
    bf16_t* AOb  = Vswz + HSD;          // [B,S,E]
    // Xb scratch lives in the TAIL of the P region (24MB of its last 48MB);
    // k_proj consumes it before k_attn overwrites all of P.
    bf16_t* Xb   = (bf16_t*)(P + PSZ - 6 * 1024 * 1024);

    k_convert<<<dim3(2048, 7), 256, 0, stream>>>(Wq, Wk, Wv, Wo, query, key_, value,
                                                 Wb, Xb);
    k_proj<<<dim3(8, 32, 3), 256, 0, stream>>>(Xb, Wb, bq, bk, bv, Qb, Kswz, Vswz);
    k_attn<<<dim3(1024), 256, 0, stream>>>(Qb, Kswz, Vswz, P, AOb);
    k_oproj<<<dim3(8, 32, 1), 256, 0, stream>>>(AOb, Wb + 3 * WSZ, bo, out);
}